// Round 1
// baseline (1201.044 us; speedup 1.0000x reference)
//
#include <hip/hip_runtime.h>
#include <hip/hip_bf16.h>
#include <cstdint>

// ---------------------------------------------------------------------------
// TransformerClassifier: 2x single-head attention (N=4, L=2048, D=1024) +
// mean-pool + linear + sigmoid.  All math on MFMA via bf16 hi/lo split
// (3-pass: hh + hl + lh) for ~fp32-equivalent accuracy at bf16 MFMA rate.
//
// ws layout (bytes):
//   [  0MB) Ahi/Alo   : X split, later overwritten by H1 split   (16+16 MB)
//   [ 32MB) Qhi/Qlo   : Q split; later aliased by H2 fp32        (16+16 MB)
//   [ 64MB) Khi/Klo   : K split                                  (16+16 MB)
//   [ 96MB) Vthi/Vtlo : V^T split (per-batch [d][l])             (16+16 MB)
//   [128MB) Wt        : 6x (W^T hi 2MB + W^T lo 2MB)             (24 MB)
//   [152MB) S/P       : scores fp32, softmax'd IN PLACE to P hi/lo rows
//                       (row l: 2048 ushort hi, then 2048 ushort lo) (64 MB)
//   total 216 MB
// ---------------------------------------------------------------------------

#define DEVFN __device__ __forceinline__

typedef __attribute__((ext_vector_type(8))) short bf16x8;
typedef __attribute__((ext_vector_type(4))) float f32x4;
typedef unsigned short u16;

DEVFN u16 f2bf(float f) {               // round-to-nearest-even bf16 (finite)
    uint32_t x = __float_as_uint(f);
    x += 0x7fffu + ((x >> 16) & 1u);
    return (u16)(x >> 16);
}
DEVFN float bf2f(u16 u) { return __uint_as_float(((uint32_t)u) << 16); }
DEVFN void split2(float v, u16& h, u16& l) {
    h = f2bf(v);
    l = f2bf(v - bf2f(h));              // exact residual (Sterbenz)
}

DEVFN void gload_lds16(const void* g, void* l) {
    // each lane loads 16B from its own global addr; deposits at
    // wave-uniform LDS base + lane*16 (guide §5)
    __builtin_amdgcn_global_load_lds(
        (const __attribute__((address_space(1))) void*)g,
        (__attribute__((address_space(3))) void*)l, 16, 0, 0);
}

// ---------------------------------------------------------------------------
// Generic 3-pass split-bf16 GEMM:  C = scale * (A . B^T)
//   A   : M x K, row-major (hi/lo arrays, shared lda)
//   B^T : N x K, row-major (hi/lo arrays, shared ldb)
// Tile 128x128, BK=32, 256 threads (4 waves, each 64x64 = 4x4 frags 16x16).
// EPI: 0 = write hi/lo split row-major (ldc, cStride)
//      1 = write fp32 row-major, scaled
//      2 = write hi/lo split transposed per-batch: out[b][col][l],
//          b = row>>11, l = row&2047  (for V^T; grid.z==1, M=8192)
// ---------------------------------------------------------------------------
template<int EPI>
__global__ __launch_bounds__(256, 2) void gemm3(
    const u16* __restrict__ Ahi, const u16* __restrict__ Alo, long long aStride,
    const u16* __restrict__ Bhi, const u16* __restrict__ Blo, long long bStride,
    void* __restrict__ out0, void* __restrict__ out1, long long cStride,
    int M, int N, int K, int lda, int ldb, int ldc, float scale)
{
    __shared__ __align__(16) u16 lds[4][128 * 32];   // Ahi, Alo, Bhi, Blo
    const int tid  = threadIdx.x;
    const int wave = tid >> 6, lane = tid & 63;
    const int bz   = blockIdx.z;
    const u16* pAhi = Ahi + (size_t)bz * aStride;
    const u16* pAlo = Alo + (size_t)bz * aStride;
    const u16* pBhi = Bhi + (size_t)bz * bStride;
    const u16* pBlo = Blo + (size_t)bz * bStride;
    const int m0 = blockIdx.y * 128, n0 = blockIdx.x * 128;
    const int sRow = lane >> 2;          // row within 16-row staging segment
    const int sKo  = (lane & 3) * 8;     // k element offset for this lane
    const int wr = (wave >> 1) * 64, wc = (wave & 1) * 64;
    const int fr = lane & 15, fk = (lane >> 4) * 8;

    f32x4 acc[4][4] = {};

    for (int k0 = 0; k0 < K; k0 += 32) {
#pragma unroll
        for (int c = 0; c < 2; c++) {
            const int s   = wave * 2 + c;          // segment 0..7 (16 rows each)
            const int row = s * 16 + sRow;
            gload_lds16(pAhi + (size_t)(m0 + row) * lda + (k0 + sKo), &lds[0][s * 512]);
            gload_lds16(pAlo + (size_t)(m0 + row) * lda + (k0 + sKo), &lds[1][s * 512]);
            gload_lds16(pBhi + (size_t)(n0 + row) * ldb + (k0 + sKo), &lds[2][s * 512]);
            gload_lds16(pBlo + (size_t)(n0 + row) * ldb + (k0 + sKo), &lds[3][s * 512]);
        }
        __syncthreads();   // compiler drains vmcnt(0) before barrier

        bf16x8 ah[4], al[4], bh[4], bl[4];
#pragma unroll
        for (int i = 0; i < 4; i++) {
            ah[i] = *(const bf16x8*)&lds[0][(wr + i * 16 + fr) * 32 + fk];
            al[i] = *(const bf16x8*)&lds[1][(wr + i * 16 + fr) * 32 + fk];
            bh[i] = *(const bf16x8*)&lds[2][(wc + i * 16 + fr) * 32 + fk];
            bl[i] = *(const bf16x8*)&lds[3][(wc + i * 16 + fr) * 32 + fk];
        }
#pragma unroll
        for (int i = 0; i < 4; i++)
#pragma unroll
            for (int j = 0; j < 4; j++) {
                acc[i][j] = __builtin_amdgcn_mfma_f32_16x16x32_bf16(ah[i], bh[j], acc[i][j], 0, 0, 0);
                acc[i][j] = __builtin_amdgcn_mfma_f32_16x16x32_bf16(ah[i], bl[j], acc[i][j], 0, 0, 0);
                acc[i][j] = __builtin_amdgcn_mfma_f32_16x16x32_bf16(al[i], bh[j], acc[i][j], 0, 0, 0);
            }
        __syncthreads();
    }

    // epilogue: C/D layout col = lane&15, row = (lane>>4)*4 + r  (guide §3)
#pragma unroll
    for (int i = 0; i < 4; i++)
#pragma unroll
        for (int j = 0; j < 4; j++)
#pragma unroll
            for (int r = 0; r < 4; r++) {
                const int row = m0 + wr + i * 16 + (lane >> 4) * 4 + r;
                const int col = n0 + wc + j * 16 + (lane & 15);
                const float v = acc[i][j][r] * scale;
                if constexpr (EPI == 0) {
                    u16 h, l; split2(v, h, l);
                    const size_t off = (size_t)bz * cStride + (size_t)row * ldc + col;
                    ((u16*)out0)[off] = h;
                    ((u16*)out1)[off] = l;
                } else if constexpr (EPI == 1) {
                    ((float*)out0)[(size_t)bz * cStride + (size_t)row * ldc + col] = v;
                } else {  // EPI == 2 : V^T split, per-batch (L=2048, D=1024)
                    const int b = row >> 11, ll = row & 2047;
                    const size_t off = (size_t)b * (2048 * 1024) + (size_t)col * 2048 + ll;
                    u16 h, l; split2(v, h, l);
                    ((u16*)out0)[off] = h;
                    ((u16*)out1)[off] = l;
                }
            }
}

// ---------------------------------------------------------------------------
// split fp32 -> hi/lo bf16 (flat, 4 elems/thread, n divisible by 1024)
// ---------------------------------------------------------------------------
__global__ __launch_bounds__(256) void split_f32(
    const float* __restrict__ x, u16* __restrict__ hi, u16* __restrict__ lo)
{
    const size_t i = ((size_t)blockIdx.x * 256 + threadIdx.x) * 4;
    const float4 v = *(const float4*)&x[i];
    ushort4 h, l;
    split2(v.x, h.x, l.x); split2(v.y, h.y, l.y);
    split2(v.z, h.z, l.z); split2(v.w, h.w, l.w);
    *(ushort4*)&hi[i] = h;
    *(ushort4*)&lo[i] = l;
}

// ---------------------------------------------------------------------------
// W (1024x1024 fp32, [d][k]) -> W^T hi/lo bf16 ([k][d]).  64x64 LDS tiles.
// ---------------------------------------------------------------------------
__global__ __launch_bounds__(256) void transpose_split(
    const float* __restrict__ W, u16* __restrict__ thi, u16* __restrict__ tlo)
{
    __shared__ float t[64][65];
    const int tid = threadIdx.x;
    const int r0 = blockIdx.y * 64, c0 = blockIdx.x * 64;
#pragma unroll
    for (int it = 0; it < 16; it++) {
        const int idx = it * 256 + tid, rr = idx >> 6, cc = idx & 63;
        t[rr][cc] = W[(size_t)(r0 + rr) * 1024 + (c0 + cc)];
    }
    __syncthreads();
#pragma unroll
    for (int it = 0; it < 16; it++) {
        const int idx = it * 256 + tid, nn = idx >> 6, kk = idx & 63;
        const float v = t[kk][nn];
        u16 h, l; split2(v, h, l);
        const size_t off = (size_t)(c0 + nn) * 1024 + (r0 + kk);
        thi[off] = h;
        tlo[off] = l;
    }
}

// ---------------------------------------------------------------------------
// Row softmax over 2048 fp32 scores, written IN PLACE as P hi/lo bf16:
// row byte layout after: [2048 u16 hi][2048 u16 lo]  (same 8KB footprint)
// ---------------------------------------------------------------------------
__global__ __launch_bounds__(256) void softmax_rows(float* __restrict__ S)
{
    const int r   = blockIdx.x;                 // 0..8191 (batch*2048 + l)
    float* row    = S + (size_t)r * 2048;
    const int tid = threadIdx.x;

    const float4 a = *(const float4*)&row[tid * 8];
    const float4 b = *(const float4*)&row[tid * 8 + 4];
    float v[8] = {a.x, a.y, a.z, a.w, b.x, b.y, b.z, b.w};

    float m = v[0];
#pragma unroll
    for (int j = 1; j < 8; j++) m = fmaxf(m, v[j]);
    for (int o = 32; o; o >>= 1) m = fmaxf(m, __shfl_xor(m, o));
    __shared__ float redm[4], reds[4];
    if ((tid & 63) == 0) redm[tid >> 6] = m;
    __syncthreads();
    m = fmaxf(fmaxf(redm[0], redm[1]), fmaxf(redm[2], redm[3]));

    float e[8], s = 0.f;
#pragma unroll
    for (int j = 0; j < 8; j++) { e[j] = __expf(v[j] - m); s += e[j]; }
    for (int o = 32; o; o >>= 1) s += __shfl_xor(s, o);
    if ((tid & 63) == 0) reds[tid >> 6] = s;
    __syncthreads();
    s = reds[0] + reds[1] + reds[2] + reds[3];
    const float inv = 1.f / s;

    u16* ph = (u16*)row;          // all reads of this row completed (barriers)
    u16* pl = ph + 2048;
#pragma unroll
    for (int j = 0; j < 8; j++) {
        u16 h, l; split2(e[j] * inv, h, l);
        ph[tid * 8 + j] = h;
        pl[tid * 8 + j] = l;
    }
}

// ---------------------------------------------------------------------------
// pooled = mean over L of H2; out[b] = sigmoid(pooled . W_O + b_O)
// ---------------------------------------------------------------------------
__global__ __launch_bounds__(256) void pool_head(
    const float* __restrict__ H2, const float* __restrict__ wO,
    const float* __restrict__ bO, float* __restrict__ out)
{
    const int b   = blockIdx.x;
    const int tid = threadIdx.x;
    const float* Hb = H2 + (size_t)b * 2048 * 1024;
    float dot = 0.f;
    for (int d = tid; d < 1024; d += 256) {
        float s = 0.f;
        for (int l = 0; l < 2048; l++) s += Hb[(size_t)l * 1024 + d];
        dot += s * wO[d];
    }
    __shared__ float red[256];
    red[tid] = dot;
    __syncthreads();
    for (int st = 128; st; st >>= 1) {
        if (tid < st) red[tid] += red[tid + st];
        __syncthreads();
    }
    if (tid == 0) {
        const float logit = red[0] * (1.f / 2048.f) + bO[0];
        out[b] = 1.f / (1.f + __expf(-logit));
    }
}

// ---------------------------------------------------------------------------
extern "C" void kernel_launch(void* const* d_in, const int* in_sizes, int n_in,
                              void* d_out, int out_size, void* d_ws, size_t ws_size,
                              hipStream_t stream)
{
    const float* X   = (const float*)d_in[0];
    const float* Wq1 = (const float*)d_in[1];
    const float* Wk1 = (const float*)d_in[2];
    const float* Wv1 = (const float*)d_in[3];
    const float* Wq2 = (const float*)d_in[4];
    const float* Wk2 = (const float*)d_in[5];
    const float* Wv2 = (const float*)d_in[6];
    const float* WO  = (const float*)d_in[7];
    const float* bO  = (const float*)d_in[8];
    float* out = (float*)d_out;

    uint8_t* ws = (uint8_t*)d_ws;
    const size_t MB = 1ull << 20;
    u16* Ahi  = (u16*)(ws + 0);        u16* Alo  = (u16*)(ws + 16 * MB);
    u16* Qhi  = (u16*)(ws + 32 * MB);  u16* Qlo  = (u16*)(ws + 48 * MB);
    u16* Khi  = (u16*)(ws + 64 * MB);  u16* Klo  = (u16*)(ws + 80 * MB);
    u16* Vthi = (u16*)(ws + 96 * MB);  u16* Vtlo = (u16*)(ws + 112 * MB);
    u16* Wt   = (u16*)(ws + 128 * MB);               // 6 x (hi 1M + lo 1M) u16
    float* S  = (float*)(ws + 152 * MB);             // 64 MB scores / P
    float* H2 = (float*)(ws + 32 * MB);              // aliases Q (dead by then)

    auto Wh = [&](int i) { return Wt + (size_t)i * 2097152; };
    auto Wl = [&](int i) { return Wt + (size_t)i * 2097152 + 1048576; };
    const float* Wsrc[6] = {Wq1, Wk1, Wv1, Wq2, Wk2, Wv2};

    // ---- prep: split X, transpose+split weights
    split_f32<<<8192, 256, 0, stream>>>(X, Ahi, Alo);   // 8M elems
    for (int i = 0; i < 6; i++)
        transpose_split<<<dim3(16, 16), 256, 0, stream>>>(Wsrc[i], Wh(i), Wl(i));

    const long long LD2 = 2048LL * 1024;   // 2M: Q/K/V & H batch stride
    const long long SST = 2048LL * 2048;   // 4M: S batch stride (floats)
    const long long PST = 2048LL * 4096;   // 8M: P batch stride (u16)

    for (int blk = 0; blk < 2; blk++) {
        const int w0 = blk * 3;
        // projections: Q, K row-major split; V transposed split
        gemm3<0><<<dim3(8, 64, 1), 256, 0, stream>>>(
            Ahi, Alo, 0, Wh(w0 + 0), Wl(w0 + 0), 0, Qhi, Qlo, 0,
            8192, 1024, 1024, 1024, 1024, 1024, 1.f);
        gemm3<0><<<dim3(8, 64, 1), 256, 0, stream>>>(
            Ahi, Alo, 0, Wh(w0 + 1), Wl(w0 + 1), 0, Khi, Klo, 0,
            8192, 1024, 1024, 1024, 1024, 1024, 1.f);
        gemm3<2><<<dim3(8, 64, 1), 256, 0, stream>>>(
            Ahi, Alo, 0, Wh(w0 + 2), Wl(w0 + 2), 0, Vthi, Vtlo, 0,
            8192, 1024, 1024, 1024, 1024, 1024, 1.f);
        // S = Q.K^T / sqrt(D)   (batched over 4)
        gemm3<1><<<dim3(16, 16, 4), 256, 0, stream>>>(
            Qhi, Qlo, LD2, Khi, Klo, LD2, S, nullptr, SST,
            2048, 2048, 1024, 1024, 1024, 2048, 0.03125f);
        // softmax rows, in-place -> P hi/lo
        softmax_rows<<<8192, 256, 0, stream>>>(S);
        // O = P.V   (A = P hi/lo interleaved rows, B^T = V^T)
        if (blk == 0) {
            gemm3<0><<<dim3(8, 16, 4), 256, 0, stream>>>(
                (u16*)S, (u16*)S + 2048, PST, Vthi, Vtlo, LD2, Ahi, Alo, LD2,
                2048, 1024, 2048, 4096, 2048, 1024, 1.f);   // H1 split -> A region
        } else {
            gemm3<1><<<dim3(8, 16, 4), 256, 0, stream>>>(
                (u16*)S, (u16*)S + 2048, PST, Vthi, Vtlo, LD2, H2, nullptr, LD2,
                2048, 1024, 2048, 4096, 2048, 1024, 1.f);   // H2 fp32
        }
    }

    pool_head<<<4, 256, 0, stream>>>(H2, WO, bO, out);
}

// Round 2
// 892.136 us; speedup vs baseline: 1.3463x; 1.3463x over previous
//
#include <hip/hip_runtime.h>
#include <hip/hip_bf16.h>
#include <cstdint>

// ---------------------------------------------------------------------------
// TransformerClassifier: 2x single-head attention (N=4, L=2048, D=1024) +
// mean-pool + linear + sigmoid.  All math on MFMA via bf16 hi/lo split
// (3-pass: hh + hl + lh) for ~fp32-equivalent accuracy at bf16 MFMA rate.
//
// ws layout (bytes):
//   [  0MB) Ahi/Alo   : X split, later overwritten by H1 split   (16+16 MB)
//   [ 32MB) Qhi/Qlo   : Q split; later aliased by H2 fp32        (16+16 MB)
//   [ 64MB) Khi/Klo   : K split (dead after blk-2 QK^T; partials reuse) (32 MB)
//   [ 96MB) Vthi/Vtlo : V^T split (per-batch [d][l])             (16+16 MB)
//   [128MB) Wt        : 6x (W^T hi 2MB + W^T lo 2MB)             (24 MB)
//   [152MB) S/P       : scores fp32, softmax'd IN PLACE to P hi/lo rows
//                       (row l: 2048 ushort hi, then 2048 ushort lo) (64 MB)
//   total 216 MB
// ---------------------------------------------------------------------------

#define DEVFN __device__ __forceinline__

typedef __attribute__((ext_vector_type(8))) short bf16x8;
typedef __attribute__((ext_vector_type(4))) float f32x4;
typedef unsigned short u16;

DEVFN u16 f2bf(float f) {               // round-to-nearest-even bf16 (finite)
    uint32_t x = __float_as_uint(f);
    x += 0x7fffu + ((x >> 16) & 1u);
    return (u16)(x >> 16);
}
DEVFN float bf2f(u16 u) { return __uint_as_float(((uint32_t)u) << 16); }
DEVFN void split2(float v, u16& h, u16& l) {
    h = f2bf(v);
    l = f2bf(v - bf2f(h));              // exact residual
}

DEVFN void gload_lds16(const void* g, void* l) {
    __builtin_amdgcn_global_load_lds(
        (const __attribute__((address_space(1))) void*)g,
        (__attribute__((address_space(3))) void*)l, 16, 0, 0);
}

// ---------------------------------------------------------------------------
// Generic 3-pass split-bf16 GEMM:  C = scale * (A . B^T)
//   A   : M x K, row-major (hi/lo arrays, shared lda)
//   B^T : N x K, row-major (hi/lo arrays, shared ldb)
// Tile 128x128, BK=32, 256 threads (4 waves, each 64x64 = 4x4 frags 16x16).
// EPI: 0 = write hi/lo split row-major; 1 = fp32 row-major; 2 = V^T split
// ---------------------------------------------------------------------------
template<int EPI>
__global__ __launch_bounds__(256, 2) void gemm3(
    const u16* __restrict__ Ahi, const u16* __restrict__ Alo, long long aStride,
    const u16* __restrict__ Bhi, const u16* __restrict__ Blo, long long bStride,
    void* __restrict__ out0, void* __restrict__ out1, long long cStride,
    int M, int N, int K, int lda, int ldb, int ldc, float scale)
{
    __shared__ __align__(16) u16 lds[4][128 * 32];   // Ahi, Alo, Bhi, Blo
    const int tid  = threadIdx.x;
    const int wave = tid >> 6, lane = tid & 63;
    const int bz   = blockIdx.z;
    const u16* pAhi = Ahi + (size_t)bz * aStride;
    const u16* pAlo = Alo + (size_t)bz * aStride;
    const u16* pBhi = Bhi + (size_t)bz * bStride;
    const u16* pBlo = Blo + (size_t)bz * bStride;
    const int m0 = blockIdx.y * 128, n0 = blockIdx.x * 128;
    const int sRow = lane >> 2;          // row within 16-row staging segment
    const int sKo  = (lane & 3) * 8;     // k element offset for this lane
    const int wr = (wave >> 1) * 64, wc = (wave & 1) * 64;
    const int fr = lane & 15, fk = (lane >> 4) * 8;

    f32x4 acc[4][4] = {};

    for (int k0 = 0; k0 < K; k0 += 32) {
#pragma unroll
        for (int c = 0; c < 2; c++) {
            const int s   = wave * 2 + c;          // segment 0..7 (16 rows each)
            const int row = s * 16 + sRow;
            gload_lds16(pAhi + (size_t)(m0 + row) * lda + (k0 + sKo), &lds[0][s * 512]);
            gload_lds16(pAlo + (size_t)(m0 + row) * lda + (k0 + sKo), &lds[1][s * 512]);
            gload_lds16(pBhi + (size_t)(n0 + row) * ldb + (k0 + sKo), &lds[2][s * 512]);
            gload_lds16(pBlo + (size_t)(n0 + row) * ldb + (k0 + sKo), &lds[3][s * 512]);
        }
        __syncthreads();

        bf16x8 ah[4], al[4], bh[4], bl[4];
#pragma unroll
        for (int i = 0; i < 4; i++) {
            ah[i] = *(const bf16x8*)&lds[0][(wr + i * 16 + fr) * 32 + fk];
            al[i] = *(const bf16x8*)&lds[1][(wr + i * 16 + fr) * 32 + fk];
            bh[i] = *(const bf16x8*)&lds[2][(wc + i * 16 + fr) * 32 + fk];
            bl[i] = *(const bf16x8*)&lds[3][(wc + i * 16 + fr) * 32 + fk];
        }
#pragma unroll
        for (int i = 0; i < 4; i++)
#pragma unroll
            for (int j = 0; j < 4; j++) {
                acc[i][j] = __builtin_amdgcn_mfma_f32_16x16x32_bf16(ah[i], bh[j], acc[i][j], 0, 0, 0);
                acc[i][j] = __builtin_amdgcn_mfma_f32_16x16x32_bf16(ah[i], bl[j], acc[i][j], 0, 0, 0);
                acc[i][j] = __builtin_amdgcn_mfma_f32_16x16x32_bf16(al[i], bh[j], acc[i][j], 0, 0, 0);
            }
        __syncthreads();
    }

    // epilogue: C/D layout col = lane&15, row = (lane>>4)*4 + r  (guide §3)
#pragma unroll
    for (int i = 0; i < 4; i++)
#pragma unroll
        for (int j = 0; j < 4; j++)
#pragma unroll
            for (int r = 0; r < 4; r++) {
                const int row = m0 + wr + i * 16 + (lane >> 4) * 4 + r;
                const int col = n0 + wc + j * 16 + (lane & 15);
                const float v = acc[i][j][r] * scale;
                if constexpr (EPI == 0) {
                    u16 h, l; split2(v, h, l);
                    const size_t off = (size_t)bz * cStride + (size_t)row * ldc + col;
                    ((u16*)out0)[off] = h;
                    ((u16*)out1)[off] = l;
                } else if constexpr (EPI == 1) {
                    ((float*)out0)[(size_t)bz * cStride + (size_t)row * ldc + col] = v;
                } else {  // EPI == 2 : V^T split, per-batch (L=2048, D=1024)
                    const int b = row >> 11, ll = row & 2047;
                    const size_t off = (size_t)b * (2048 * 1024) + (size_t)col * 2048 + ll;
                    u16 h, l; split2(v, h, l);
                    ((u16*)out0)[off] = h;
                    ((u16*)out1)[off] = l;
                }
            }
}

// ---------------------------------------------------------------------------
__global__ __launch_bounds__(256) void split_f32(
    const float* __restrict__ x, u16* __restrict__ hi, u16* __restrict__ lo)
{
    const size_t i = ((size_t)blockIdx.x * 256 + threadIdx.x) * 4;
    const float4 v = *(const float4*)&x[i];
    ushort4 h, l;
    split2(v.x, h.x, l.x); split2(v.y, h.y, l.y);
    split2(v.z, h.z, l.z); split2(v.w, h.w, l.w);
    *(ushort4*)&hi[i] = h;
    *(ushort4*)&lo[i] = l;
}

// ---------------------------------------------------------------------------
__global__ __launch_bounds__(256) void transpose_split(
    const float* __restrict__ W, u16* __restrict__ thi, u16* __restrict__ tlo)
{
    __shared__ float t[64][65];
    const int tid = threadIdx.x;
    const int r0 = blockIdx.y * 64, c0 = blockIdx.x * 64;
#pragma unroll
    for (int it = 0; it < 16; it++) {
        const int idx = it * 256 + tid, rr = idx >> 6, cc = idx & 63;
        t[rr][cc] = W[(size_t)(r0 + rr) * 1024 + (c0 + cc)];
    }
    __syncthreads();
#pragma unroll
    for (int it = 0; it < 16; it++) {
        const int idx = it * 256 + tid, nn = idx >> 6, kk = idx & 63;
        const float v = t[kk][nn];
        u16 h, l; split2(v, h, l);
        const size_t off = (size_t)(c0 + nn) * 1024 + (r0 + kk);
        thi[off] = h;
        tlo[off] = l;
    }
}

// ---------------------------------------------------------------------------
// Row softmax over 2048 fp32 scores, written IN PLACE as P hi/lo bf16
// ---------------------------------------------------------------------------
__global__ __launch_bounds__(256) void softmax_rows(float* __restrict__ S)
{
    const int r   = blockIdx.x;                 // 0..8191 (batch*2048 + l)
    float* row    = S + (size_t)r * 2048;
    const int tid = threadIdx.x;

    const float4 a = *(const float4*)&row[tid * 8];
    const float4 b = *(const float4*)&row[tid * 8 + 4];
    float v[8] = {a.x, a.y, a.z, a.w, b.x, b.y, b.z, b.w};

    float m = v[0];
#pragma unroll
    for (int j = 1; j < 8; j++) m = fmaxf(m, v[j]);
    for (int o = 32; o; o >>= 1) m = fmaxf(m, __shfl_xor(m, o));
    __shared__ float redm[4], reds[4];
    if ((tid & 63) == 0) redm[tid >> 6] = m;
    __syncthreads();
    m = fmaxf(fmaxf(redm[0], redm[1]), fmaxf(redm[2], redm[3]));

    float e[8], s = 0.f;
#pragma unroll
    for (int j = 0; j < 8; j++) { e[j] = __expf(v[j] - m); s += e[j]; }
    for (int o = 32; o; o >>= 1) s += __shfl_xor(s, o);
    if ((tid & 63) == 0) reds[tid >> 6] = s;
    __syncthreads();
    s = reds[0] + reds[1] + reds[2] + reds[3];
    const float inv = 1.f / s;

    u16* ph = (u16*)row;
    u16* pl = ph + 2048;
#pragma unroll
    for (int j = 0; j < 8; j++) {
        u16 h, l; split2(e[j] * inv, h, l);
        ph[tid * 8 + j] = h;
        pl[tid * 8 + j] = l;
    }
}

// ---------------------------------------------------------------------------
// Stage 1: per-(batch, 64-row-chunk) fused  sum_l ( H2[l,:] . W_O )
//   grid (4, 32), 256 threads; thread tid covers d = 4*tid..4*tid+3
// ---------------------------------------------------------------------------
__global__ __launch_bounds__(256) void pool_partial(
    const float* __restrict__ H2, const float* __restrict__ wO,
    float* __restrict__ partial)
{
    const int b = blockIdx.x, chunk = blockIdx.y;
    const int tid = threadIdx.x;
    const float* Hb = H2 + (size_t)b * 2048 * 1024 + (size_t)chunk * 64 * 1024;
    const float4 w = *(const float4*)&wO[tid * 4];
    float acc = 0.f;
#pragma unroll 4
    for (int l = 0; l < 64; l++) {
        const float4 h = *(const float4*)&Hb[(size_t)l * 1024 + tid * 4];
        acc += h.x * w.x + h.y * w.y + h.z * w.z + h.w * w.w;
    }
    for (int o = 32; o; o >>= 1) acc += __shfl_xor(acc, o);
    __shared__ float red[4];
    if ((tid & 63) == 0) red[tid >> 6] = acc;
    __syncthreads();
    if (tid == 0) partial[b * 32 + chunk] = red[0] + red[1] + red[2] + red[3];
}

// Stage 2: out[b] = sigmoid( mean + b_O )
__global__ void head_final(const float* __restrict__ partial,
                           const float* __restrict__ bO, float* __restrict__ out)
{
    const int b = threadIdx.x;                  // 0..3
    if (b >= 4) return;
    float s = 0.f;
#pragma unroll
    for (int c = 0; c < 32; c++) s += partial[b * 32 + c];
    const float logit = s * (1.f / 2048.f) + bO[0];
    out[b] = 1.f / (1.f + __expf(-logit));
}

// ---------------------------------------------------------------------------
extern "C" void kernel_launch(void* const* d_in, const int* in_sizes, int n_in,
                              void* d_out, int out_size, void* d_ws, size_t ws_size,
                              hipStream_t stream)
{
    const float* X   = (const float*)d_in[0];
    const float* Wq1 = (const float*)d_in[1];
    const float* Wk1 = (const float*)d_in[2];
    const float* Wv1 = (const float*)d_in[3];
    const float* Wq2 = (const float*)d_in[4];
    const float* Wk2 = (const float*)d_in[5];
    const float* Wv2 = (const float*)d_in[6];
    const float* WO  = (const float*)d_in[7];
    const float* bO  = (const float*)d_in[8];
    float* out = (float*)d_out;

    uint8_t* ws = (uint8_t*)d_ws;
    const size_t MB = 1ull << 20;
    u16* Ahi  = (u16*)(ws + 0);        u16* Alo  = (u16*)(ws + 16 * MB);
    u16* Qhi  = (u16*)(ws + 32 * MB);  u16* Qlo  = (u16*)(ws + 48 * MB);
    u16* Khi  = (u16*)(ws + 64 * MB);  u16* Klo  = (u16*)(ws + 80 * MB);
    u16* Vthi = (u16*)(ws + 96 * MB);  u16* Vtlo = (u16*)(ws + 112 * MB);
    u16* Wt   = (u16*)(ws + 128 * MB);               // 6 x (hi 1M + lo 1M) u16
    float* S  = (float*)(ws + 152 * MB);             // 64 MB scores / P
    float* H2 = (float*)(ws + 32 * MB);              // aliases Q (dead by then)
    float* partial = (float*)(ws + 64 * MB);         // aliases K (dead by then)

    auto Wh = [&](int i) { return Wt + (size_t)i * 2097152; };
    auto Wl = [&](int i) { return Wt + (size_t)i * 2097152 + 1048576; };
    const float* Wsrc[6] = {Wq1, Wk1, Wv1, Wq2, Wk2, Wv2};

    // ---- prep: split X, transpose+split weights
    split_f32<<<8192, 256, 0, stream>>>(X, Ahi, Alo);   // 8M elems
    for (int i = 0; i < 6; i++)
        transpose_split<<<dim3(16, 16), 256, 0, stream>>>(Wsrc[i], Wh(i), Wl(i));

    const long long LD2 = 2048LL * 1024;   // 2M: Q/K/V & H batch stride
    const long long SST = 2048LL * 2048;   // 4M: S batch stride (floats)
    const long long PST = 2048LL * 4096;   // 8M: P batch stride (u16)

    for (int blk = 0; blk < 2; blk++) {
        const int w0 = blk * 3;
        // projections: Q, K row-major split; V transposed split
        gemm3<0><<<dim3(8, 64, 1), 256, 0, stream>>>(
            Ahi, Alo, 0, Wh(w0 + 0), Wl(w0 + 0), 0, Qhi, Qlo, 0,
            8192, 1024, 1024, 1024, 1024, 1024, 1.f);
        gemm3<0><<<dim3(8, 64, 1), 256, 0, stream>>>(
            Ahi, Alo, 0, Wh(w0 + 1), Wl(w0 + 1), 0, Khi, Klo, 0,
            8192, 1024, 1024, 1024, 1024, 1024, 1.f);
        gemm3<2><<<dim3(8, 64, 1), 256, 0, stream>>>(
            Ahi, Alo, 0, Wh(w0 + 2), Wl(w0 + 2), 0, Vthi, Vtlo, 0,
            8192, 1024, 1024, 1024, 1024, 1024, 1.f);
        // S = Q.K^T / sqrt(D)   (batched over 4)
        gemm3<1><<<dim3(16, 16, 4), 256, 0, stream>>>(
            Qhi, Qlo, LD2, Khi, Klo, LD2, S, nullptr, SST,
            2048, 2048, 1024, 1024, 1024, 2048, 0.03125f);
        // softmax rows, in-place -> P hi/lo
        softmax_rows<<<8192, 256, 0, stream>>>(S);
        // O = P.V   (A = P hi/lo interleaved rows, B^T = V^T)
        if (blk == 0) {
            gemm3<0><<<dim3(8, 16, 4), 256, 0, stream>>>(
                (u16*)S, (u16*)S + 2048, PST, Vthi, Vtlo, LD2, Ahi, Alo, LD2,
                2048, 1024, 2048, 4096, 2048, 1024, 1.f);   // H1 split -> A region
        } else {
            gemm3<1><<<dim3(8, 16, 4), 256, 0, stream>>>(
                (u16*)S, (u16*)S + 2048, PST, Vthi, Vtlo, LD2, H2, nullptr, LD2,
                2048, 1024, 2048, 4096, 2048, 1024, 1.f);   // H2 fp32
        }
    }

    pool_partial<<<dim3(4, 32), 256, 0, stream>>>(H2, WO, partial);
    head_final<<<1, 64, 0, stream>>>(partial, bO, out);
}

// Round 3
// 800.197 us; speedup vs baseline: 1.5009x; 1.1149x over previous
//
#include <hip/hip_runtime.h>
#include <hip/hip_bf16.h>
#include <cstdint>

// ---------------------------------------------------------------------------
// TransformerClassifier: 2x single-head attention (N=4, L=2048, D=1024) +
// mean-pool + linear + sigmoid.  All math on MFMA via bf16 hi/lo split
// (3-pass: hh + hl + lh) for ~fp32-equivalent accuracy at bf16 MFMA rate.
//
// GEMM LDS: hi/lo interleaved per row -> [128 rows][8 slots x 16B] per
// operand, XOR-swizzled (slot = chunk ^ (row&7)) so ds_read_b128 fragment
// reads are bank-conflict-free.  global_load_lds keeps a LINEAR dest; the
// swizzle is realized by pre-swizzling each lane's GLOBAL source (rule #21).
//
// ws layout (bytes):
//   [  0MB) Ahi/Alo   : X split, later overwritten by H1 split   (16+16 MB)
//   [ 32MB) Qhi/Qlo   : Q split; later aliased by H2 fp32        (16+16 MB)
//   [ 64MB) Khi/Klo   : K split (dead after blk-2 QK^T; partials reuse) (32 MB)
//   [ 96MB) Vthi/Vtlo : V^T split (per-batch [d][l])             (16+16 MB)
//   [128MB) Wt        : 6x (W^T hi 2MB + W^T lo 2MB)             (24 MB)
//   [152MB) S/P       : scores fp32, softmax'd IN PLACE to P hi/lo rows
//   total 216 MB
// ---------------------------------------------------------------------------

#define DEVFN __device__ __forceinline__

typedef __attribute__((ext_vector_type(8))) short bf16x8;
typedef __attribute__((ext_vector_type(4))) float f32x4;
typedef unsigned short u16;

DEVFN u16 f2bf(float f) {               // round-to-nearest-even bf16 (finite)
    uint32_t x = __float_as_uint(f);
    x += 0x7fffu + ((x >> 16) & 1u);
    return (u16)(x >> 16);
}
DEVFN float bf2f(u16 u) { return __uint_as_float(((uint32_t)u) << 16); }
DEVFN void split2(float v, u16& h, u16& l) {
    h = f2bf(v);
    l = f2bf(v - bf2f(h));              // exact residual
}

DEVFN void gload_lds16(const void* g, void* l) {
    __builtin_amdgcn_global_load_lds(
        (const __attribute__((address_space(1))) void*)g,
        (__attribute__((address_space(3))) void*)l, 16, 0, 0);
}

// ---------------------------------------------------------------------------
// Generic 3-pass split-bf16 GEMM:  C = scale * (A . B^T)
//   A   : M x K row-major (hi/lo arrays, shared lda);  B^T : N x K row-major
// Tile 128x128, BK=32, 256 threads (4 waves, each 64x64 = 4x4 frags 16x16).
// EPI: 0 = write hi/lo split row-major; 1 = fp32 row-major; 2 = V^T split
// ---------------------------------------------------------------------------
template<int EPI>
__global__ __launch_bounds__(256, 2) void gemm3(
    const u16* __restrict__ Ahi, const u16* __restrict__ Alo, long long aStride,
    const u16* __restrict__ Bhi, const u16* __restrict__ Blo, long long bStride,
    void* __restrict__ out0, void* __restrict__ out1, long long cStride,
    int M, int N, int K, int lda, int ldb, int ldc, float scale)
{
    __shared__ __align__(16) u16 ldsA[128 * 64];   // [row][slot*8] hi/lo interleaved
    __shared__ __align__(16) u16 ldsB[128 * 64];
    const int tid  = threadIdx.x;
    const int wave = tid >> 6, lane = tid & 63;

    // --- bijective XCD-aware block swizzle (all launches have nwg % 8 == 0)
    const int gx = gridDim.x, gy = gridDim.y;
    const int nwg = gx * gy * gridDim.z;
    int flat = (blockIdx.z * gy + blockIdx.y) * gx + blockIdx.x;
    flat = (flat & 7) * (nwg >> 3) + (flat >> 3);
    const int bx = flat % gx, by = (flat / gx) % gy, bz = flat / (gx * gy);

    const u16* pAhi = Ahi + (size_t)bz * aStride;
    const u16* pAlo = Alo + (size_t)bz * aStride;
    const u16* pBhi = Bhi + (size_t)bz * bStride;
    const u16* pBlo = Blo + (size_t)bz * bStride;
    const int m0 = by * 128, n0 = bx * 128;

    // staging: lane l covers (row r0+(l>>3), slot l&7); slot holds logical
    // chunk c = (l&7) ^ (l>>3)  (c<4: hi k-chunk c; c>=4: lo k-chunk c-4)
    const int c    = (lane & 7) ^ (lane >> 3);
    const int rsub = lane >> 3;
    const int koff = (c & 3) * 8;
    const u16* aSrc[4];
    const u16* bSrc[4];
#pragma unroll
    for (int t = 0; t < 4; t++) {
        const int r = wave * 32 + t * 8 + rsub;
        aSrc[t] = (c < 4 ? pAhi : pAlo) + (size_t)(m0 + r) * lda + koff;
        bSrc[t] = (c < 4 ? pBhi : pBlo) + (size_t)(n0 + r) * ldb + koff;
    }

    // fragment read indices (u16 units), constant across K
    const int fr = lane & 15, ch = lane >> 4;         // hi chunk = ch (0..3)
    const int wr = (wave >> 1) * 64, wc = (wave & 1) * 64;
    int aIdx[4], bIdx[4];
#pragma unroll
    for (int i = 0; i < 4; i++) {
        const int rA = wr + i * 16 + fr;
        aIdx[i] = rA * 64 + ((ch ^ (rA & 7)) * 8);
        const int rB = wc + i * 16 + fr;
        bIdx[i] = rB * 64 + ((ch ^ (rB & 7)) * 8);
    }

    f32x4 acc[4][4] = {};

    for (int k0 = 0; k0 < K; k0 += 32) {
#pragma unroll
        for (int t = 0; t < 4; t++) {
            const int r0 = wave * 32 + t * 8;          // wave-uniform LDS base
            gload_lds16(aSrc[t], &ldsA[r0 * 64]);
            gload_lds16(bSrc[t], &ldsB[r0 * 64]);
            aSrc[t] += 32;
            bSrc[t] += 32;
        }
        __syncthreads();

        bf16x8 ah[4], al[4], bh[4], bl[4];
#pragma unroll
        for (int i = 0; i < 4; i++) {
            ah[i] = *(const bf16x8*)&ldsA[aIdx[i]];
            al[i] = *(const bf16x8*)&ldsA[aIdx[i] ^ 32];   // slot ^ 4
            bh[i] = *(const bf16x8*)&ldsB[bIdx[i]];
            bl[i] = *(const bf16x8*)&ldsB[bIdx[i] ^ 32];
        }
#pragma unroll
        for (int i = 0; i < 4; i++)
#pragma unroll
            for (int j = 0; j < 4; j++) {
                acc[i][j] = __builtin_amdgcn_mfma_f32_16x16x32_bf16(ah[i], bh[j], acc[i][j], 0, 0, 0);
                acc[i][j] = __builtin_amdgcn_mfma_f32_16x16x32_bf16(ah[i], bl[j], acc[i][j], 0, 0, 0);
                acc[i][j] = __builtin_amdgcn_mfma_f32_16x16x32_bf16(al[i], bh[j], acc[i][j], 0, 0, 0);
            }
        __syncthreads();
    }

    // epilogue: C/D layout col = lane&15, row = (lane>>4)*4 + r  (guide §3)
#pragma unroll
    for (int i = 0; i < 4; i++)
#pragma unroll
        for (int j = 0; j < 4; j++)
#pragma unroll
            for (int r = 0; r < 4; r++) {
                const int row = m0 + wr + i * 16 + (lane >> 4) * 4 + r;
                const int col = n0 + wc + j * 16 + (lane & 15);
                const float v = acc[i][j][r] * scale;
                if constexpr (EPI == 0) {
                    u16 h, l; split2(v, h, l);
                    const size_t off = (size_t)bz * cStride + (size_t)row * ldc + col;
                    ((u16*)out0)[off] = h;
                    ((u16*)out1)[off] = l;
                } else if constexpr (EPI == 1) {
                    ((float*)out0)[(size_t)bz * cStride + (size_t)row * ldc + col] = v;
                } else {  // EPI == 2 : V^T split, per-batch (L=2048, D=1024)
                    const int b = row >> 11, ll = row & 2047;
                    const size_t off = (size_t)b * (2048 * 1024) + (size_t)col * 2048 + ll;
                    u16 h, l; split2(v, h, l);
                    ((u16*)out0)[off] = h;
                    ((u16*)out1)[off] = l;
                }
            }
}

// ---------------------------------------------------------------------------
__global__ __launch_bounds__(256) void split_f32(
    const float* __restrict__ x, u16* __restrict__ hi, u16* __restrict__ lo)
{
    const size_t i = ((size_t)blockIdx.x * 256 + threadIdx.x) * 4;
    const float4 v = *(const float4*)&x[i];
    ushort4 h, l;
    split2(v.x, h.x, l.x); split2(v.y, h.y, l.y);
    split2(v.z, h.z, l.z); split2(v.w, h.w, l.w);
    *(ushort4*)&hi[i] = h;
    *(ushort4*)&lo[i] = l;
}

// ---------------------------------------------------------------------------
__global__ __launch_bounds__(256) void transpose_split(
    const float* __restrict__ W, u16* __restrict__ thi, u16* __restrict__ tlo)
{
    __shared__ float t[64][65];
    const int tid = threadIdx.x;
    const int r0 = blockIdx.y * 64, c0 = blockIdx.x * 64;
#pragma unroll
    for (int it = 0; it < 16; it++) {
        const int idx = it * 256 + tid, rr = idx >> 6, cc = idx & 63;
        t[rr][cc] = W[(size_t)(r0 + rr) * 1024 + (c0 + cc)];
    }
    __syncthreads();
#pragma unroll
    for (int it = 0; it < 16; it++) {
        const int idx = it * 256 + tid, nn = idx >> 6, kk = idx & 63;
        const float v = t[kk][nn];
        u16 h, l; split2(v, h, l);
        const size_t off = (size_t)(c0 + nn) * 1024 + (r0 + kk);
        thi[off] = h;
        tlo[off] = l;
    }
}

// ---------------------------------------------------------------------------
// Row softmax over 2048 fp32 scores, written IN PLACE as P hi/lo bf16
// ---------------------------------------------------------------------------
__global__ __launch_bounds__(256) void softmax_rows(float* __restrict__ S)
{
    const int r   = blockIdx.x;                 // 0..8191 (batch*2048 + l)
    float* row    = S + (size_t)r * 2048;
    const int tid = threadIdx.x;

    const float4 a = *(const float4*)&row[tid * 8];
    const float4 b = *(const float4*)&row[tid * 8 + 4];
    float v[8] = {a.x, a.y, a.z, a.w, b.x, b.y, b.z, b.w};

    float m = v[0];
#pragma unroll
    for (int j = 1; j < 8; j++) m = fmaxf(m, v[j]);
    for (int o = 32; o; o >>= 1) m = fmaxf(m, __shfl_xor(m, o));
    __shared__ float redm[4], reds[4];
    if ((tid & 63) == 0) redm[tid >> 6] = m;
    __syncthreads();
    m = fmaxf(fmaxf(redm[0], redm[1]), fmaxf(redm[2], redm[3]));

    float e[8], s = 0.f;
#pragma unroll
    for (int j = 0; j < 8; j++) { e[j] = __expf(v[j] - m); s += e[j]; }
    for (int o = 32; o; o >>= 1) s += __shfl_xor(s, o);
    if ((tid & 63) == 0) reds[tid >> 6] = s;
    __syncthreads();
    s = reds[0] + reds[1] + reds[2] + reds[3];
    const float inv = 1.f / s;

    u16* ph = (u16*)row;
    u16* pl = ph + 2048;
#pragma unroll
    for (int j = 0; j < 8; j++) {
        u16 h, l; split2(e[j] * inv, h, l);
        ph[tid * 8 + j] = h;
        pl[tid * 8 + j] = l;
    }
}

// ---------------------------------------------------------------------------
// Stage 1: per-(batch, 64-row-chunk) fused  sum_l ( H2[l,:] . W_O )
// ---------------------------------------------------------------------------
__global__ __launch_bounds__(256) void pool_partial(
    const float* __restrict__ H2, const float* __restrict__ wO,
    float* __restrict__ partial)
{
    const int b = blockIdx.x, chunk = blockIdx.y;
    const int tid = threadIdx.x;
    const float* Hb = H2 + (size_t)b * 2048 * 1024 + (size_t)chunk * 64 * 1024;
    const float4 w = *(const float4*)&wO[tid * 4];
    float acc = 0.f;
#pragma unroll 4
    for (int l = 0; l < 64; l++) {
        const float4 h = *(const float4*)&Hb[(size_t)l * 1024 + tid * 4];
        acc += h.x * w.x + h.y * w.y + h.z * w.z + h.w * w.w;
    }
    for (int o = 32; o; o >>= 1) acc += __shfl_xor(acc, o);
    __shared__ float red[4];
    if ((tid & 63) == 0) red[tid >> 6] = acc;
    __syncthreads();
    if (tid == 0) partial[b * 32 + chunk] = red[0] + red[1] + red[2] + red[3];
}

// Stage 2: out[b] = sigmoid( mean + b_O )
__global__ void head_final(const float* __restrict__ partial,
                           const float* __restrict__ bO, float* __restrict__ out)
{
    const int b = threadIdx.x;                  // 0..3
    if (b >= 4) return;
    float s = 0.f;
#pragma unroll
    for (int c = 0; c < 32; c++) s += partial[b * 32 + c];
    const float logit = s * (1.f / 2048.f) + bO[0];
    out[b] = 1.f / (1.f + __expf(-logit));
}

// ---------------------------------------------------------------------------
extern "C" void kernel_launch(void* const* d_in, const int* in_sizes, int n_in,
                              void* d_out, int out_size, void* d_ws, size_t ws_size,
                              hipStream_t stream)
{
    const float* X   = (const float*)d_in[0];
    const float* Wq1 = (const float*)d_in[1];
    const float* Wk1 = (const float*)d_in[2];
    const float* Wv1 = (const float*)d_in[3];
    const float* Wq2 = (const float*)d_in[4];
    const float* Wk2 = (const float*)d_in[5];
    const float* Wv2 = (const float*)d_in[6];
    const float* WO  = (const float*)d_in[7];
    const float* bO  = (const float*)d_in[8];
    float* out = (float*)d_out;

    uint8_t* ws = (uint8_t*)d_ws;
    const size_t MB = 1ull << 20;
    u16* Ahi  = (u16*)(ws + 0);        u16* Alo  = (u16*)(ws + 16 * MB);
    u16* Qhi  = (u16*)(ws + 32 * MB);  u16* Qlo  = (u16*)(ws + 48 * MB);
    u16* Khi  = (u16*)(ws + 64 * MB);  u16* Klo  = (u16*)(ws + 80 * MB);
    u16* Vthi = (u16*)(ws + 96 * MB);  u16* Vtlo = (u16*)(ws + 112 * MB);
    u16* Wt   = (u16*)(ws + 128 * MB);               // 6 x (hi 1M + lo 1M) u16
    float* S  = (float*)(ws + 152 * MB);             // 64 MB scores / P
    float* H2 = (float*)(ws + 32 * MB);              // aliases Q (dead by then)
    float* partial = (float*)(ws + 64 * MB);         // aliases K (dead by then)

    auto Wh = [&](int i) { return Wt + (size_t)i * 2097152; };
    auto Wl = [&](int i) { return Wt + (size_t)i * 2097152 + 1048576; };
    const float* Wsrc[6] = {Wq1, Wk1, Wv1, Wq2, Wk2, Wv2};

    // ---- prep: split X, transpose+split weights
    split_f32<<<8192, 256, 0, stream>>>(X, Ahi, Alo);   // 8M elems
    for (int i = 0; i < 6; i++)
        transpose_split<<<dim3(16, 16), 256, 0, stream>>>(Wsrc[i], Wh(i), Wl(i));

    const long long LD2 = 2048LL * 1024;   // 2M: Q/K/V & H batch stride
    const long long SST = 2048LL * 2048;   // 4M: S batch stride (floats)
    const long long PST = 2048LL * 4096;   // 8M: P batch stride (u16)

    for (int blk = 0; blk < 2; blk++) {
        const int w0 = blk * 3;
        // projections: Q, K row-major split; V transposed split
        gemm3<0><<<dim3(8, 64, 1), 256, 0, stream>>>(
            Ahi, Alo, 0, Wh(w0 + 0), Wl(w0 + 0), 0, Qhi, Qlo, 0,
            8192, 1024, 1024, 1024, 1024, 1024, 1.f);
        gemm3<0><<<dim3(8, 64, 1), 256, 0, stream>>>(
            Ahi, Alo, 0, Wh(w0 + 1), Wl(w0 + 1), 0, Khi, Klo, 0,
            8192, 1024, 1024, 1024, 1024, 1024, 1.f);
        gemm3<2><<<dim3(8, 64, 1), 256, 0, stream>>>(
            Ahi, Alo, 0, Wh(w0 + 2), Wl(w0 + 2), 0, Vthi, Vtlo, 0,
            8192, 1024, 1024, 1024, 1024, 1024, 1.f);
        // S = Q.K^T / sqrt(D)   (batched over 4)
        gemm3<1><<<dim3(16, 16, 4), 256, 0, stream>>>(
            Qhi, Qlo, LD2, Khi, Klo, LD2, S, nullptr, SST,
            2048, 2048, 1024, 1024, 1024, 2048, 0.03125f);
        // softmax rows, in-place -> P hi/lo
        softmax_rows<<<8192, 256, 0, stream>>>(S);
        // O = P.V   (A = P hi/lo interleaved rows, B^T = V^T)
        if (blk == 0) {
            gemm3<0><<<dim3(8, 16, 4), 256, 0, stream>>>(
                (u16*)S, (u16*)S + 2048, PST, Vthi, Vtlo, LD2, Ahi, Alo, LD2,
                2048, 1024, 2048, 4096, 2048, 1024, 1.f);   // H1 split -> A region
        } else {
            gemm3<1><<<dim3(8, 16, 4), 256, 0, stream>>>(
                (u16*)S, (u16*)S + 2048, PST, Vthi, Vtlo, LD2, H2, nullptr, LD2,
                2048, 1024, 2048, 4096, 2048, 1024, 1.f);   // H2 fp32
        }
    }

    pool_partial<<<dim3(4, 32), 256, 0, stream>>>(H2, WO, partial);
    head_final<<<1, 64, 0, stream>>>(partial, bO, out);
}

// Round 4
// 793.730 us; speedup vs baseline: 1.5132x; 1.0081x over previous
//
#include <hip/hip_runtime.h>
#include <hip/hip_bf16.h>
#include <cstdint>

// ---------------------------------------------------------------------------
// TransformerClassifier: 2x single-head attention (N=4, L=2048, D=1024) +
// mean-pool + linear + sigmoid.  All math on MFMA via bf16 hi/lo split
// (3-pass: hh + hl + lh) for ~fp32-equivalent accuracy at bf16 MFMA rate.
//
// GEMM v2: BM=256 x BN=128, BK=32, 512 thr (8 waves, 4M x 2N), triple-
// buffered LDS (144 KiB), prefetch distance 2, counted vmcnt(6), 4 phases
// per K-tile with {ds_read || stage-issue, barrier, lgkmcnt(0), setprio,
// 12 MFMA, barrier}.  LDS rows hold 8 x 16B slots (hi chunks 0-3, lo 4-7),
// XOR-swizzled slot = chunk ^ (row&7); realized by pre-swizzled GLOBAL
// source addresses (global_load_lds dest stays linear, rule #21).
//
// ws layout unchanged (216 MB total).
// ---------------------------------------------------------------------------

#define DEVFN __device__ __forceinline__

typedef __attribute__((ext_vector_type(8))) short bf16x8;
typedef __attribute__((ext_vector_type(4))) float f32x4;
typedef unsigned short u16;

DEVFN u16 f2bf(float f) {               // round-to-nearest-even bf16 (finite)
    uint32_t x = __float_as_uint(f);
    x += 0x7fffu + ((x >> 16) & 1u);
    return (u16)(x >> 16);
}
DEVFN float bf2f(u16 u) { return __uint_as_float(((uint32_t)u) << 16); }
DEVFN void split2(float v, u16& h, u16& l) {
    h = f2bf(v);
    l = f2bf(v - bf2f(h));              // exact residual
}

DEVFN void gload_lds16(const void* g, void* l) {
    __builtin_amdgcn_global_load_lds(
        (const __attribute__((address_space(1))) void*)g,
        (__attribute__((address_space(3))) void*)l, 16, 0, 0);
}

#define MFMA_BF16 __builtin_amdgcn_mfma_f32_16x16x32_bf16

// ---------------------------------------------------------------------------
// 3-pass split-bf16 GEMM:  C = scale * (A . B^T)
//   A : M x K row-major (hi/lo, shared lda); B^T : N x K row-major (hi/lo)
// EPI: 0 = hi/lo split row-major; 1 = fp32 row-major; 2 = V^T split
// Requires M%256==0, N%128==0, K%32==0, K/32 >= 3, grid (N/128, M/256, Z),
// total blocks % 8 == 0.
// ---------------------------------------------------------------------------
template<int EPI>
__global__ __launch_bounds__(512, 2) void gemm3(
    const u16* __restrict__ Ahi, const u16* __restrict__ Alo, long long aStride,
    const u16* __restrict__ Bhi, const u16* __restrict__ Blo, long long bStride,
    void* __restrict__ out0, void* __restrict__ out1, long long cStride,
    int M, int N, int K, int lda, int ldb, int ldc, float scale)
{
    // per buffer: A 256x64 u16 (32KB) + B 128x64 u16 (16KB) = 24576 u16
    __shared__ __align__(16) u16 L[3 * 24576];      // 144 KiB
    const int tid  = threadIdx.x;
    const int wave = tid >> 6, lane = tid & 63;

    // bijective XCD-aware block swizzle (all launches have nwg % 8 == 0)
    const int gx = gridDim.x, gy = gridDim.y;
    const int nwg = gx * gy * gridDim.z;
    int flat = (blockIdx.z * gy + blockIdx.y) * gx + blockIdx.x;
    flat = (flat & 7) * (nwg >> 3) + (flat >> 3);
    const int bx = flat % gx, by = (flat / gx) % gy, bz = flat / (gx * gy);

    const u16* pAhi = Ahi + (size_t)bz * aStride;
    const u16* pAlo = Alo + (size_t)bz * aStride;
    const u16* pBhi = Bhi + (size_t)bz * bStride;
    const u16* pBlo = Blo + (size_t)bz * bStride;
    const int m0 = by * 256, n0 = bx * 128;

    // ---- staging setup: 6 issues/thread per K-tile (A:4, B:2).
    // linear slot s covers (row = s>>3, slot = s&7); stored chunk =
    // slot ^ (row&7); chunk<4 -> hi k-chunk, else lo k-chunk (chunk&3).
    const u16* src[6];
    int dstOff[6];
#pragma unroll
    for (int q = 0; q < 4; q++) {
        const int s = q * 512 + tid, row = s >> 3, c = (s & 7) ^ (row & 7);
        src[q]    = (c < 4 ? pAhi : pAlo) + (size_t)(m0 + row) * lda + (c & 3) * 8;
        dstOff[q] = q * 4096 + wave * 512;
    }
#pragma unroll
    for (int q = 0; q < 2; q++) {
        const int s = q * 512 + tid, row = s >> 3, c = (s & 7) ^ (row & 7);
        src[4 + q]    = (c < 4 ? pBhi : pBlo) + (size_t)(n0 + row) * ldb + (c & 3) * 8;
        dstOff[4 + q] = 16384 + q * 4096 + wave * 512;
    }

    // ---- fragment read indices (u16 units within a buffer)
    const int fr = lane & 15, ch = lane >> 4;       // hi k-chunk = ch
    const int wm = (wave >> 1) * 64, wn = (wave & 1) * 64;
    int aIdx[4], bIdx[4];
#pragma unroll
    for (int i = 0; i < 4; i++) {
        const int rA = wm + i * 16 + fr;
        aIdx[i] = rA * 64 + ((ch ^ (rA & 7)) * 8);
        const int rB = wn + i * 16 + fr;
        bIdx[i] = 16384 + rB * 64 + ((ch ^ (rB & 7)) * 8);
    }

    const int NT = K >> 5;

    // ---- prologue: stage K-tiles 0,1 into buffers 0,1
#pragma unroll
    for (int i = 0; i < 6; i++) gload_lds16(src[i], &L[dstOff[i]]);
#pragma unroll
    for (int i = 0; i < 6; i++) src[i] += 32;
#pragma unroll
    for (int i = 0; i < 6; i++) gload_lds16(src[i], &L[24576 + dstOff[i]]);
#pragma unroll
    for (int i = 0; i < 6; i++) src[i] += 32;
    asm volatile("s_waitcnt vmcnt(6)" ::: "memory");
    __builtin_amdgcn_s_barrier();

    f32x4 acc[4][4] = {};
    int cOff = 0, sOff = 2 * 24576;     // compute-buffer / stage-buffer offsets

    for (int kt = 0; kt < NT; ++kt) {
        const bool pre = (kt + 2) < NT;
        bf16x8 bh[4], bl[4];
        bf16x8 ah, al;

        // ---------------- phase 0: b(8) + a0(2) reads, 2 stage issues
#pragma unroll
        for (int n = 0; n < 4; n++) {
            bh[n] = *(const bf16x8*)&L[cOff + bIdx[n]];
            bl[n] = *(const bf16x8*)&L[cOff + (bIdx[n] ^ 32)];
        }
        ah = *(const bf16x8*)&L[cOff + aIdx[0]];
        al = *(const bf16x8*)&L[cOff + (aIdx[0] ^ 32)];
        if (pre) { gload_lds16(src[0], &L[sOff + dstOff[0]]);
                   gload_lds16(src[1], &L[sOff + dstOff[1]]); }
        __builtin_amdgcn_s_barrier();
        asm volatile("s_waitcnt lgkmcnt(0)" ::: "memory");
        __builtin_amdgcn_sched_barrier(0);
        __builtin_amdgcn_s_setprio(1);
#pragma unroll
        for (int n = 0; n < 4; n++) {
            acc[0][n] = MFMA_BF16(ah, bh[n], acc[0][n], 0, 0, 0);
            acc[0][n] = MFMA_BF16(ah, bl[n], acc[0][n], 0, 0, 0);
            acc[0][n] = MFMA_BF16(al, bh[n], acc[0][n], 0, 0, 0);
        }
        __builtin_amdgcn_s_setprio(0);
        __builtin_amdgcn_s_barrier();

        // ---------------- phases 1..3: a(2) reads, stage issues {2,1,1}
#pragma unroll
        for (int p = 1; p < 4; p++) {
            ah = *(const bf16x8*)&L[cOff + aIdx[p]];
            al = *(const bf16x8*)&L[cOff + (aIdx[p] ^ 32)];
            if (pre) {
                if (p == 1) { gload_lds16(src[2], &L[sOff + dstOff[2]]);
                              gload_lds16(src[3], &L[sOff + dstOff[3]]); }
                else if (p == 2) gload_lds16(src[4], &L[sOff + dstOff[4]]);
                else             gload_lds16(src[5], &L[sOff + dstOff[5]]);
            }
            __builtin_amdgcn_s_barrier();
            asm volatile("s_waitcnt lgkmcnt(0)" ::: "memory");
            __builtin_amdgcn_sched_barrier(0);
            __builtin_amdgcn_s_setprio(1);
#pragma unroll
            for (int n = 0; n < 4; n++) {
                acc[p][n] = MFMA_BF16(ah, bh[n], acc[p][n], 0, 0, 0);
                acc[p][n] = MFMA_BF16(ah, bl[n], acc[p][n], 0, 0, 0);
                acc[p][n] = MFMA_BF16(al, bh[n], acc[p][n], 0, 0, 0);
            }
            __builtin_amdgcn_s_setprio(0);
            if (p < 3) __builtin_amdgcn_s_barrier();
        }

        // ---- K-tile boundary: kt+1 must be fully staged (counted wait)
        if (pre)                 asm volatile("s_waitcnt vmcnt(6)" ::: "memory");
        else if (kt + 1 < NT)    asm volatile("s_waitcnt vmcnt(0)" ::: "memory");
        __builtin_amdgcn_sched_barrier(0);
        __builtin_amdgcn_s_barrier();

        if (pre) {
#pragma unroll
            for (int i = 0; i < 6; i++) src[i] += 32;
        }
        cOff += 24576; if (cOff == 3 * 24576) cOff = 0;
        sOff += 24576; if (sOff == 3 * 24576) sOff = 0;
    }

    // ---- epilogue: C/D layout col = lane&15, row = (lane>>4)*4 + r
#pragma unroll
    for (int i = 0; i < 4; i++)
#pragma unroll
        for (int j = 0; j < 4; j++)
#pragma unroll
            for (int r = 0; r < 4; r++) {
                const int row = m0 + wm + i * 16 + (lane >> 4) * 4 + r;
                const int col = n0 + wn + j * 16 + (lane & 15);
                const float v = acc[i][j][r] * scale;
                if constexpr (EPI == 0) {
                    u16 h, l; split2(v, h, l);
                    const size_t off = (size_t)bz * cStride + (size_t)row * ldc + col;
                    ((u16*)out0)[off] = h;
                    ((u16*)out1)[off] = l;
                } else if constexpr (EPI == 1) {
                    ((float*)out0)[(size_t)bz * cStride + (size_t)row * ldc + col] = v;
                } else {  // EPI == 2 : V^T split, per-batch (L=2048, D=1024)
                    const int b = row >> 11, ll = row & 2047;
                    const size_t off = (size_t)b * (2048 * 1024) + (size_t)col * 2048 + ll;
                    u16 h, l; split2(v, h, l);
                    ((u16*)out0)[off] = h;
                    ((u16*)out1)[off] = l;
                }
            }
}

// ---------------------------------------------------------------------------
__global__ __launch_bounds__(256) void split_f32(
    const float* __restrict__ x, u16* __restrict__ hi, u16* __restrict__ lo)
{
    const size_t i = ((size_t)blockIdx.x * 256 + threadIdx.x) * 4;
    const float4 v = *(const float4*)&x[i];
    ushort4 h, l;
    split2(v.x, h.x, l.x); split2(v.y, h.y, l.y);
    split2(v.z, h.z, l.z); split2(v.w, h.w, l.w);
    *(ushort4*)&hi[i] = h;
    *(ushort4*)&lo[i] = l;
}

// ---------------------------------------------------------------------------
__global__ __launch_bounds__(256) void transpose_split(
    const float* __restrict__ W, u16* __restrict__ thi, u16* __restrict__ tlo)
{
    __shared__ float t[64][65];
    const int tid = threadIdx.x;
    const int r0 = blockIdx.y * 64, c0 = blockIdx.x * 64;
#pragma unroll
    for (int it = 0; it < 16; it++) {
        const int idx = it * 256 + tid, rr = idx >> 6, cc = idx & 63;
        t[rr][cc] = W[(size_t)(r0 + rr) * 1024 + (c0 + cc)];
    }
    __syncthreads();
#pragma unroll
    for (int it = 0; it < 16; it++) {
        const int idx = it * 256 + tid, nn = idx >> 6, kk = idx & 63;
        const float v = t[kk][nn];
        u16 h, l; split2(v, h, l);
        const size_t off = (size_t)(c0 + nn) * 1024 + (r0 + kk);
        thi[off] = h;
        tlo[off] = l;
    }
}

// ---------------------------------------------------------------------------
// Row softmax over 2048 fp32 scores, written IN PLACE as P hi/lo bf16
// ---------------------------------------------------------------------------
__global__ __launch_bounds__(256) void softmax_rows(float* __restrict__ S)
{
    const int r   = blockIdx.x;                 // 0..8191 (batch*2048 + l)
    float* row    = S + (size_t)r * 2048;
    const int tid = threadIdx.x;

    const float4 a = *(const float4*)&row[tid * 8];
    const float4 b = *(const float4*)&row[tid * 8 + 4];
    float v[8] = {a.x, a.y, a.z, a.w, b.x, b.y, b.z, b.w};

    float m = v[0];
#pragma unroll
    for (int j = 1; j < 8; j++) m = fmaxf(m, v[j]);
    for (int o = 32; o; o >>= 1) m = fmaxf(m, __shfl_xor(m, o));
    __shared__ float redm[4], reds[4];
    if ((tid & 63) == 0) redm[tid >> 6] = m;
    __syncthreads();
    m = fmaxf(fmaxf(redm[0], redm[1]), fmaxf(redm[2], redm[3]));

    float e[8], s = 0.f;
#pragma unroll
    for (int j = 0; j < 8; j++) { e[j] = __expf(v[j] - m); s += e[j]; }
    for (int o = 32; o; o >>= 1) s += __shfl_xor(s, o);
    if ((tid & 63) == 0) reds[tid >> 6] = s;
    __syncthreads();
    s = reds[0] + reds[1] + reds[2] + reds[3];
    const float inv = 1.f / s;

    u16* ph = (u16*)row;
    u16* pl = ph + 2048;
#pragma unroll
    for (int j = 0; j < 8; j++) {
        u16 h, l; split2(e[j] * inv, h, l);
        ph[tid * 8 + j] = h;
        pl[tid * 8 + j] = l;
    }
}

// ---------------------------------------------------------------------------
__global__ __launch_bounds__(256) void pool_partial(
    const float* __restrict__ H2, const float* __restrict__ wO,
    float* __restrict__ partial)
{
    const int b = blockIdx.x, chunk = blockIdx.y;
    const int tid = threadIdx.x;
    const float* Hb = H2 + (size_t)b * 2048 * 1024 + (size_t)chunk * 64 * 1024;
    const float4 w = *(const float4*)&wO[tid * 4];
    float acc = 0.f;
#pragma unroll 4
    for (int l = 0; l < 64; l++) {
        const float4 h = *(const float4*)&Hb[(size_t)l * 1024 + tid * 4];
        acc += h.x * w.x + h.y * w.y + h.z * w.z + h.w * w.w;
    }
    for (int o = 32; o; o >>= 1) acc += __shfl_xor(acc, o);
    __shared__ float red[4];
    if ((tid & 63) == 0) red[tid >> 6] = acc;
    __syncthreads();
    if (tid == 0) partial[b * 32 + chunk] = red[0] + red[1] + red[2] + red[3];
}

__global__ void head_final(const float* __restrict__ partial,
                           const float* __restrict__ bO, float* __restrict__ out)
{
    const int b = threadIdx.x;                  // 0..3
    if (b >= 4) return;
    float s = 0.f;
#pragma unroll
    for (int c = 0; c < 32; c++) s += partial[b * 32 + c];
    const float logit = s * (1.f / 2048.f) + bO[0];
    out[b] = 1.f / (1.f + __expf(-logit));
}

// ---------------------------------------------------------------------------
extern "C" void kernel_launch(void* const* d_in, const int* in_sizes, int n_in,
                              void* d_out, int out_size, void* d_ws, size_t ws_size,
                              hipStream_t stream)
{
    const float* X   = (const float*)d_in[0];
    const float* Wq1 = (const float*)d_in[1];
    const float* Wk1 = (const float*)d_in[2];
    const float* Wv1 = (const float*)d_in[3];
    const float* Wq2 = (const float*)d_in[4];
    const float* Wk2 = (const float*)d_in[5];
    const float* Wv2 = (const float*)d_in[6];
    const float* WO  = (const float*)d_in[7];
    const float* bO  = (const float*)d_in[8];
    float* out = (float*)d_out;

    uint8_t* ws = (uint8_t*)d_ws;
    const size_t MB = 1ull << 20;
    u16* Ahi  = (u16*)(ws + 0);        u16* Alo  = (u16*)(ws + 16 * MB);
    u16* Qhi  = (u16*)(ws + 32 * MB);  u16* Qlo  = (u16*)(ws + 48 * MB);
    u16* Khi  = (u16*)(ws + 64 * MB);  u16* Klo  = (u16*)(ws + 80 * MB);
    u16* Vthi = (u16*)(ws + 96 * MB);  u16* Vtlo = (u16*)(ws + 112 * MB);
    u16* Wt   = (u16*)(ws + 128 * MB);               // 6 x (hi 1M + lo 1M) u16
    float* S  = (float*)(ws + 152 * MB);             // 64 MB scores / P
    float* H2 = (float*)(ws + 32 * MB);              // aliases Q (dead by then)
    float* partial = (float*)(ws + 64 * MB);         // aliases K (dead by then)

    auto Wh = [&](int i) { return Wt + (size_t)i * 2097152; };
    auto Wl = [&](int i) { return Wt + (size_t)i * 2097152 + 1048576; };
    const float* Wsrc[6] = {Wq1, Wk1, Wv1, Wq2, Wk2, Wv2};

    // ---- prep: split X, transpose+split weights
    split_f32<<<8192, 256, 0, stream>>>(X, Ahi, Alo);   // 8M elems
    for (int i = 0; i < 6; i++)
        transpose_split<<<dim3(16, 16), 256, 0, stream>>>(Wsrc[i], Wh(i), Wl(i));

    const long long LD2 = 2048LL * 1024;   // 2M: Q/K/V & H batch stride
    const long long SST = 2048LL * 2048;   // 4M: S batch stride (floats)
    const long long PST = 2048LL * 4096;   // 8M: P batch stride (u16)

    for (int blk = 0; blk < 2; blk++) {
        const int w0 = blk * 3;
        // projections: grid (N/128=8, M/256=32) = 256 blocks
        gemm3<0><<<dim3(8, 32, 1), 512, 0, stream>>>(
            Ahi, Alo, 0, Wh(w0 + 0), Wl(w0 + 0), 0, Qhi, Qlo, 0,
            8192, 1024, 1024, 1024, 1024, 1024, 1.f);
        gemm3<0><<<dim3(8, 32, 1), 512, 0, stream>>>(
            Ahi, Alo, 0, Wh(w0 + 1), Wl(w0 + 1), 0, Khi, Klo, 0,
            8192, 1024, 1024, 1024, 1024, 1024, 1.f);
        gemm3<2><<<dim3(8, 32, 1), 512, 0, stream>>>(
            Ahi, Alo, 0, Wh(w0 + 2), Wl(w0 + 2), 0, Vthi, Vtlo, 0,
            8192, 1024, 1024, 1024, 1024, 1024, 1.f);
        // S = Q.K^T / sqrt(D): grid (2048/128=16, 2048/256=8, 4) = 512 blocks
        gemm3<1><<<dim3(16, 8, 4), 512, 0, stream>>>(
            Qhi, Qlo, LD2, Khi, Klo, LD2, S, nullptr, SST,
            2048, 2048, 1024, 1024, 1024, 2048, 0.03125f);
        // softmax rows, in-place -> P hi/lo
        softmax_rows<<<8192, 256, 0, stream>>>(S);
        // O = P.V: grid (1024/128=8, 2048/256=8, 4) = 256 blocks
        if (blk == 0) {
            gemm3<0><<<dim3(8, 8, 4), 512, 0, stream>>>(
                (u16*)S, (u16*)S + 2048, PST, Vthi, Vtlo, LD2, Ahi, Alo, LD2,
                2048, 1024, 2048, 4096, 2048, 1024, 1.f);   // H1 split -> A region
        } else {
            gemm3<1><<<dim3(8, 8, 4), 512, 0, stream>>>(
                (u16*)S, (u16*)S + 2048, PST, Vthi, Vtlo, LD2, H2, nullptr, LD2,
                2048, 1024, 2048, 4096, 2048, 1024, 1.f);   // H2 fp32
        }
    }

    pool_partial<<<dim3(4, 32), 256, 0, stream>>>(H2, WO, partial);
    head_final<<<1, 64, 0, stream>>>(partial, bO, out);
}

// Round 5
// 774.030 us; speedup vs baseline: 1.5517x; 1.0255x over previous
//
#include <hip/hip_runtime.h>
#include <hip/hip_bf16.h>
#include <cstdint>

// ---------------------------------------------------------------------------
// TransformerClassifier: 2x single-head attention (N=4, L=2048, D=1024) +
// mean-pool + linear + sigmoid.  All math on MFMA via bf16 hi/lo split
// (3-pass: hh + hl + lh) for ~fp32-equivalent accuracy at bf16 MFMA rate.
//
// GEMM v3 (m201-style): BN=256, BM templated (256 QK^T / 128 proj+PV),
// 512 thr = 8 waves 2M x 4N (wave tile BM/2 x 64), BK=32, double-buffered
// LDS, 4 quadrant-phases per K-tile: each phase {quadrant ds_reads + 2
// stage issues, barrier, lgkmcnt(0), sched_barrier, setprio(1), MFMAs,
// setprio(0), barrier}; vmcnt(0) once per K-tile at the boundary (stage
// issues happen >=3 phases earlier).  LDS rows = 8 x 16B slots (hi chunks
// 0-3, lo 4-7), XOR-swizzled slot = chunk ^ (row&7), realized by
// pre-swizzled GLOBAL source addrs (global_load_lds dest linear, rule #21).
//
// ws layout unchanged (216 MB total).
// ---------------------------------------------------------------------------

#define DEVFN __device__ __forceinline__

typedef __attribute__((ext_vector_type(8))) short bf16x8;
typedef __attribute__((ext_vector_type(4))) float f32x4;
typedef unsigned short u16;

DEVFN u16 f2bf(float f) {               // round-to-nearest-even bf16 (finite)
    uint32_t x = __float_as_uint(f);
    x += 0x7fffu + ((x >> 16) & 1u);
    return (u16)(x >> 16);
}
DEVFN float bf2f(u16 u) { return __uint_as_float(((uint32_t)u) << 16); }
DEVFN void split2(float v, u16& h, u16& l) {
    h = f2bf(v);
    l = f2bf(v - bf2f(h));              // exact residual
}

DEVFN void gload_lds16(const void* g, void* l) {
    __builtin_amdgcn_global_load_lds(
        (const __attribute__((address_space(1))) void*)g,
        (__attribute__((address_space(3))) void*)l, 16, 0, 0);
}

#define MFMA_BF16 __builtin_amdgcn_mfma_f32_16x16x32_bf16

// ---------------------------------------------------------------------------
// 3-pass split-bf16 GEMM:  C = scale * (A . B^T)
//   A : M x K row-major (hi/lo, shared lda); B^T : N x K row-major (hi/lo)
// BN = 256 fixed.  Requires M%BM==0, N%256==0, K%32==0, K/32>=2,
// grid (N/256, M/BM, Z), total blocks % 8 == 0.
// EPI: 0 = hi/lo split row-major; 1 = fp32 row-major; 2 = V^T split
// ---------------------------------------------------------------------------
template<int BM, int EPI>
__global__ __launch_bounds__(512, 2) void gemm3(
    const u16* __restrict__ Ahi, const u16* __restrict__ Alo, long long aStride,
    const u16* __restrict__ Bhi, const u16* __restrict__ Blo, long long bStride,
    void* __restrict__ out0, void* __restrict__ out1, long long cStride,
    int M, int N, int K, int lda, int ldb, int ldc, float scale)
{
    constexpr int BUFSZ = BM * 64 + 16384;   // u16 per buffer (A + B sections)
    constexpr int AU    = BM / 64;           // A stage units per thread (4|2)
    constexpr int NU    = AU + 4;            // total stage units (8|6)
    constexpr int HF    = BM / 64;           // A-frag pairs per half (4|2)

    __shared__ __align__(16) u16 L[2 * BUFSZ];
    const int tid  = threadIdx.x;
    const int wave = tid >> 6, lane = tid & 63;

    // bijective XCD-aware block swizzle (all launches have nwg % 8 == 0)
    const int gx = gridDim.x, gy = gridDim.y;
    const int nwg = gx * gy * gridDim.z;
    int flat = (blockIdx.z * gy + blockIdx.y) * gx + blockIdx.x;
    flat = (flat & 7) * (nwg >> 3) + (flat >> 3);
    const int bx = flat % gx, by = (flat / gx) % gy, bz = flat / (gx * gy);

    const u16* pAhi = Ahi + (size_t)bz * aStride;
    const u16* pAlo = Alo + (size_t)bz * aStride;
    const u16* pBhi = Bhi + (size_t)bz * bStride;
    const u16* pBlo = Blo + (size_t)bz * bStride;
    const int m0 = by * BM, n0 = bx * 256;

    // ---- staging: unit q covers linear u16 range [q*4096, q*4096+4096)
    // of a buffer section; thread covers slot s = q*512 + tid ->
    // (row = s>>3, slot = s&7), stored chunk = slot ^ (row&7).
    const u16* src[NU];
    int dst[NU];
#pragma unroll
    for (int q = 0; q < AU; q++) {
        const int s = q * 512 + tid, row = s >> 3, c = (s & 7) ^ (row & 7);
        src[q] = (c < 4 ? pAhi : pAlo) + (size_t)(m0 + row) * lda + (c & 3) * 8;
        dst[q] = q * 4096 + wave * 512;
    }
#pragma unroll
    for (int q = 0; q < 4; q++) {
        const int s = q * 512 + tid, row = s >> 3, c = (s & 7) ^ (row & 7);
        src[AU + q] = (c < 4 ? pBhi : pBlo) + (size_t)(n0 + row) * ldb + (c & 3) * 8;
        dst[AU + q] = BM * 64 + q * 4096 + wave * 512;
    }

    // ---- fragment geometry
    const int fr = lane & 15, ch = lane >> 4;        // row-in-frag, hi k-chunk
    const int wm = (wave >> 2) * (BM / 2);           // 2M x 4N decomposition
    const int wn = (wave & 3) * 64;

    const int NT = K >> 5;

    // ---- prologue: stage tile 0 into buffer 0
#pragma unroll
    for (int u = 0; u < NU; u++) { gload_lds16(src[u], &L[dst[u]]); src[u] += 32; }
    asm volatile("s_waitcnt vmcnt(0)" ::: "memory");
    __builtin_amdgcn_s_barrier();

    f32x4 acc[2 * HF][4] = {};
    bf16x8 ah[HF], al[HF], bh[4], bl[4];
    int cOff = 0;

#define STAGE(u) do { gload_lds16(src[u], &L[sOff + dst[u]]); src[u] += 32; } while (0)
#define PH_SYNC  __builtin_amdgcn_s_barrier();                                 \
                 asm volatile("s_waitcnt lgkmcnt(0)" ::: "memory");            \
                 __builtin_amdgcn_sched_barrier(0);                            \
                 __builtin_amdgcn_s_setprio(1)
#define PH_END   __builtin_amdgcn_s_setprio(0);                                \
                 __builtin_amdgcn_s_barrier()

    for (int kt = 0; kt < NT; ++kt) {
        const int sOff = cOff ^ BUFSZ;
        const bool pre = (kt + 1) < NT;

        // ---- phase 0: read A half0 + B j0,j1; stage 0,1; quad (0,0)
#pragma unroll
        for (int i = 0; i < HF; i++) {
            const int r = wm + i * 16 + fr;
            const int x = cOff + r * 64 + ((ch ^ (r & 7)) << 3);
            ah[i] = *(const bf16x8*)&L[x];
            al[i] = *(const bf16x8*)&L[x ^ 32];
        }
#pragma unroll
        for (int j = 0; j < 2; j++) {
            const int r = wn + j * 16 + fr;
            const int x = cOff + BM * 64 + r * 64 + ((ch ^ (r & 7)) << 3);
            bh[j] = *(const bf16x8*)&L[x];
            bl[j] = *(const bf16x8*)&L[x ^ 32];
        }
        if (pre) { STAGE(0); STAGE(1); }
        PH_SYNC;
#pragma unroll
        for (int i = 0; i < HF; i++)
#pragma unroll
            for (int j = 0; j < 2; j++) {
                acc[i][j] = MFMA_BF16(ah[i], bh[j], acc[i][j], 0, 0, 0);
                acc[i][j] = MFMA_BF16(ah[i], bl[j], acc[i][j], 0, 0, 0);
                acc[i][j] = MFMA_BF16(al[i], bh[j], acc[i][j], 0, 0, 0);
            }
        PH_END;

        // ---- phase 1: read B j2,j3; stage 2,3; quad (0,1)
#pragma unroll
        for (int j = 2; j < 4; j++) {
            const int r = wn + j * 16 + fr;
            const int x = cOff + BM * 64 + r * 64 + ((ch ^ (r & 7)) << 3);
            bh[j] = *(const bf16x8*)&L[x];
            bl[j] = *(const bf16x8*)&L[x ^ 32];
        }
        if (pre) { STAGE(2); STAGE(3); }
        PH_SYNC;
#pragma unroll
        for (int i = 0; i < HF; i++)
#pragma unroll
            for (int j = 2; j < 4; j++) {
                acc[i][j] = MFMA_BF16(ah[i], bh[j], acc[i][j], 0, 0, 0);
                acc[i][j] = MFMA_BF16(ah[i], bl[j], acc[i][j], 0, 0, 0);
                acc[i][j] = MFMA_BF16(al[i], bh[j], acc[i][j], 0, 0, 0);
            }
        PH_END;

        // ---- phase 2: read A half1; stage 4,5; quad (1,0)
#pragma unroll
        for (int i = 0; i < HF; i++) {
            const int r = wm + (BM / 4) + i * 16 + fr;
            const int x = cOff + r * 64 + ((ch ^ (r & 7)) << 3);
            ah[i] = *(const bf16x8*)&L[x];
            al[i] = *(const bf16x8*)&L[x ^ 32];
        }
        if (pre) { STAGE(4); STAGE(5); }
        PH_SYNC;
#pragma unroll
        for (int i = 0; i < HF; i++)
#pragma unroll
            for (int j = 0; j < 2; j++) {
                acc[HF + i][j] = MFMA_BF16(ah[i], bh[j], acc[HF + i][j], 0, 0, 0);
                acc[HF + i][j] = MFMA_BF16(ah[i], bl[j], acc[HF + i][j], 0, 0, 0);
                acc[HF + i][j] = MFMA_BF16(al[i], bh[j], acc[HF + i][j], 0, 0, 0);
            }
        PH_END;

        // ---- phase 3: no reads; stage 6,7 (BM=256 only); quad (1,1)
        if (pre) {
            if constexpr (NU > 6) { STAGE(6); STAGE(7); }
        }
        __builtin_amdgcn_s_setprio(1);
#pragma unroll
        for (int i = 0; i < HF; i++)
#pragma unroll
            for (int j = 2; j < 4; j++) {
                acc[HF + i][j] = MFMA_BF16(ah[i], bh[j], acc[HF + i][j], 0, 0, 0);
                acc[HF + i][j] = MFMA_BF16(ah[i], bl[j], acc[HF + i][j], 0, 0, 0);
                acc[HF + i][j] = MFMA_BF16(al[i], bh[j], acc[HF + i][j], 0, 0, 0);
            }
        __builtin_amdgcn_s_setprio(0);

        // ---- K-tile boundary
        if (pre) asm volatile("s_waitcnt vmcnt(0)" ::: "memory");
        __builtin_amdgcn_sched_barrier(0);
        __builtin_amdgcn_s_barrier();
        cOff = sOff;
    }
#undef STAGE
#undef PH_SYNC
#undef PH_END

    // ---- epilogue: C/D layout col = lane&15, row = (lane>>4)*4 + r
#pragma unroll
    for (int i = 0; i < 2 * HF; i++)
#pragma unroll
        for (int j = 0; j < 4; j++)
#pragma unroll
            for (int r = 0; r < 4; r++) {
                const int row = m0 + wm + i * 16 + (lane >> 4) * 4 + r;
                const int col = n0 + wn + j * 16 + (lane & 15);
                const float v = acc[i][j][r] * scale;
                if constexpr (EPI == 0) {
                    u16 h, l; split2(v, h, l);
                    const size_t off = (size_t)bz * cStride + (size_t)row * ldc + col;
                    ((u16*)out0)[off] = h;
                    ((u16*)out1)[off] = l;
                } else if constexpr (EPI == 1) {
                    ((float*)out0)[(size_t)bz * cStride + (size_t)row * ldc + col] = v;
                } else {  // EPI == 2 : V^T split, per-batch (L=2048, D=1024)
                    const int b = row >> 11, ll = row & 2047;
                    const size_t off = (size_t)b * (2048 * 1024) + (size_t)col * 2048 + ll;
                    u16 h, l; split2(v, h, l);
                    ((u16*)out0)[off] = h;
                    ((u16*)out1)[off] = l;
                }
            }
}

// ---------------------------------------------------------------------------
__global__ __launch_bounds__(256) void split_f32(
    const float* __restrict__ x, u16* __restrict__ hi, u16* __restrict__ lo)
{
    const size_t i = ((size_t)blockIdx.x * 256 + threadIdx.x) * 4;
    const float4 v = *(const float4*)&x[i];
    ushort4 h, l;
    split2(v.x, h.x, l.x); split2(v.y, h.y, l.y);
    split2(v.z, h.z, l.z); split2(v.w, h.w, l.w);
    *(ushort4*)&hi[i] = h;
    *(ushort4*)&lo[i] = l;
}

// ---------------------------------------------------------------------------
__global__ __launch_bounds__(256) void transpose_split(
    const float* __restrict__ W, u16* __restrict__ thi, u16* __restrict__ tlo)
{
    __shared__ float t[64][65];
    const int tid = threadIdx.x;
    const int r0 = blockIdx.y * 64, c0 = blockIdx.x * 64;
#pragma unroll
    for (int it = 0; it < 16; it++) {
        const int idx = it * 256 + tid, rr = idx >> 6, cc = idx & 63;
        t[rr][cc] = W[(size_t)(r0 + rr) * 1024 + (c0 + cc)];
    }
    __syncthreads();
#pragma unroll
    for (int it = 0; it < 16; it++) {
        const int idx = it * 256 + tid, nn = idx >> 6, kk = idx & 63;
        const float v = t[kk][nn];
        u16 h, l; split2(v, h, l);
        const size_t off = (size_t)(c0 + nn) * 1024 + (r0 + kk);
        thi[off] = h;
        tlo[off] = l;
    }
}

// ---------------------------------------------------------------------------
// Row softmax over 2048 fp32 scores, written IN PLACE as P hi/lo bf16
// ---------------------------------------------------------------------------
__global__ __launch_bounds__(256) void softmax_rows(float* __restrict__ S)
{
    const int r   = blockIdx.x;                 // 0..8191 (batch*2048 + l)
    float* row    = S + (size_t)r * 2048;
    const int tid = threadIdx.x;

    const float4 a = *(const float4*)&row[tid * 8];
    const float4 b = *(const float4*)&row[tid * 8 + 4];
    float v[8] = {a.x, a.y, a.z, a.w, b.x, b.y, b.z, b.w};

    float m = v[0];
#pragma unroll
    for (int j = 1; j < 8; j++) m = fmaxf(m, v[j]);
    for (int o = 32; o; o >>= 1) m = fmaxf(m, __shfl_xor(m, o));
    __shared__ float redm[4], reds[4];
    if ((tid & 63) == 0) redm[tid >> 6] = m;
    __syncthreads();
    m = fmaxf(fmaxf(redm[0], redm[1]), fmaxf(redm[2], redm[3]));

    float e[8], s = 0.f;
#pragma unroll
    for (int j = 0; j < 8; j++) { e[j] = __expf(v[j] - m); s += e[j]; }
    for (int o = 32; o; o >>= 1) s += __shfl_xor(s, o);
    if ((tid & 63) == 0) reds[tid >> 6] = s;
    __syncthreads();
    s = reds[0] + reds[1] + reds[2] + reds[3];
    const float inv = 1.f / s;

    u16* ph = (u16*)row;
    u16* pl = ph + 2048;
#pragma unroll
    for (int j = 0; j < 8; j++) {
        u16 h, l; split2(e[j] * inv, h, l);
        ph[tid * 8 + j] = h;
        pl[tid * 8 + j] = l;
    }
}

// ---------------------------------------------------------------------------
__global__ __launch_bounds__(256) void pool_partial(
    const float* __restrict__ H2, const float* __restrict__ wO,
    float* __restrict__ partial)
{
    const int b = blockIdx.x, chunk = blockIdx.y;
    const int tid = threadIdx.x;
    const float* Hb = H2 + (size_t)b * 2048 * 1024 + (size_t)chunk * 64 * 1024;
    const float4 w = *(const float4*)&wO[tid * 4];
    float acc = 0.f;
#pragma unroll 4
    for (int l = 0; l < 64; l++) {
        const float4 h = *(const float4*)&Hb[(size_t)l * 1024 + tid * 4];
        acc += h.x * w.x + h.y * w.y + h.z * w.z + h.w * w.w;
    }
    for (int o = 32; o; o >>= 1) acc += __shfl_xor(acc, o);
    __shared__ float red[4];
    if ((tid & 63) == 0) red[tid >> 6] = acc;
    __syncthreads();
    if (tid == 0) partial[b * 32 + chunk] = red[0] + red[1] + red[2] + red[3];
}

__global__ void head_final(const float* __restrict__ partial,
                           const float* __restrict__ bO, float* __restrict__ out)
{
    const int b = threadIdx.x;                  // 0..3
    if (b >= 4) return;
    float s = 0.f;
#pragma unroll
    for (int c = 0; c < 32; c++) s += partial[b * 32 + c];
    const float logit = s * (1.f / 2048.f) + bO[0];
    out[b] = 1.f / (1.f + __expf(-logit));
}

// ---------------------------------------------------------------------------
extern "C" void kernel_launch(void* const* d_in, const int* in_sizes, int n_in,
                              void* d_out, int out_size, void* d_ws, size_t ws_size,
                              hipStream_t stream)
{
    const float* X   = (const float*)d_in[0];
    const float* Wq1 = (const float*)d_in[1];
    const float* Wk1 = (const float*)d_in[2];
    const float* Wv1 = (const float*)d_in[3];
    const float* Wq2 = (const float*)d_in[4];
    const float* Wk2 = (const float*)d_in[5];
    const float* Wv2 = (const float*)d_in[6];
    const float* WO  = (const float*)d_in[7];
    const float* bO  = (const float*)d_in[8];
    float* out = (float*)d_out;

    uint8_t* ws = (uint8_t*)d_ws;
    const size_t MB = 1ull << 20;
    u16* Ahi  = (u16*)(ws + 0);        u16* Alo  = (u16*)(ws + 16 * MB);
    u16* Qhi  = (u16*)(ws + 32 * MB);  u16* Qlo  = (u16*)(ws + 48 * MB);
    u16* Khi  = (u16*)(ws + 64 * MB);  u16* Klo  = (u16*)(ws + 80 * MB);
    u16* Vthi = (u16*)(ws + 96 * MB);  u16* Vtlo = (u16*)(ws + 112 * MB);
    u16* Wt   = (u16*)(ws + 128 * MB);               // 6 x (hi 1M + lo 1M) u16
    float* S  = (float*)(ws + 152 * MB);             // 64 MB scores / P
    float* H2 = (float*)(ws + 32 * MB);              // aliases Q (dead by then)
    float* partial = (float*)(ws + 64 * MB);         // aliases K (dead by then)

    auto Wh = [&](int i) { return Wt + (size_t)i * 2097152; };
    auto Wl = [&](int i) { return Wt + (size_t)i * 2097152 + 1048576; };
    const float* Wsrc[6] = {Wq1, Wk1, Wv1, Wq2, Wk2, Wv2};

    // ---- prep: split X, transpose+split weights
    split_f32<<<8192, 256, 0, stream>>>(X, Ahi, Alo);   // 8M elems
    for (int i = 0; i < 6; i++)
        transpose_split<<<dim3(16, 16), 256, 0, stream>>>(Wsrc[i], Wh(i), Wl(i));

    const long long LD2 = 2048LL * 1024;   // 2M: Q/K/V & H batch stride
    const long long SST = 2048LL * 2048;   // 4M: S batch stride (floats)
    const long long PST = 2048LL * 4096;   // 8M: P batch stride (u16)

    for (int blk = 0; blk < 2; blk++) {
        const int w0 = blk * 3;
        // projections: BM=128, BN=256 -> grid (1024/256=4, 8192/128=64) = 256
        gemm3<128, 0><<<dim3(4, 64, 1), 512, 0, stream>>>(
            Ahi, Alo, 0, Wh(w0 + 0), Wl(w0 + 0), 0, Qhi, Qlo, 0,
            8192, 1024, 1024, 1024, 1024, 1024, 1.f);
        gemm3<128, 0><<<dim3(4, 64, 1), 512, 0, stream>>>(
            Ahi, Alo, 0, Wh(w0 + 1), Wl(w0 + 1), 0, Khi, Klo, 0,
            8192, 1024, 1024, 1024, 1024, 1024, 1.f);
        gemm3<128, 2><<<dim3(4, 64, 1), 512, 0, stream>>>(
            Ahi, Alo, 0, Wh(w0 + 2), Wl(w0 + 2), 0, Vthi, Vtlo, 0,
            8192, 1024, 1024, 1024, 1024, 1024, 1.f);
        // S = Q.K^T / sqrt(D): BM=256 -> grid (2048/256=8, 2048/256=8, 4) = 256
        gemm3<256, 1><<<dim3(8, 8, 4), 512, 0, stream>>>(
            Qhi, Qlo, LD2, Khi, Klo, LD2, S, nullptr, SST,
            2048, 2048, 1024, 1024, 1024, 2048, 0.03125f);
        // softmax rows, in-place -> P hi/lo
        softmax_rows<<<8192, 256, 0, stream>>>(S);
        // O = P.V: BM=128 -> grid (1024/256=4, 2048/128=16, 4) = 256
        if (blk == 0) {
            gemm3<128, 0><<<dim3(4, 16, 4), 512, 0, stream>>>(
                (u16*)S, (u16*)S + 2048, PST, Vthi, Vtlo, LD2, Ahi, Alo, LD2,
                2048, 1024, 2048, 4096, 2048, 1024, 1.f);   // H1 split -> A region
        } else {
            gemm3<128, 1><<<dim3(4, 16, 4), 512, 0, stream>>>(
                (u16*)S, (u16*)S + 2048, PST, Vthi, Vtlo, LD2, H2, nullptr, LD2,
                2048, 1024, 2048, 4096, 2048, 1024, 1.f);   // H2 fp32
        }
    }

    pool_partial<<<dim3(4, 32), 256, 0, stream>>>(H2, WO, partial);
    head_final<<<1, 64, 0, stream>>>(partial, bO, out);
}

// Round 6
// 772.354 us; speedup vs baseline: 1.5550x; 1.0022x over previous
//
#include <hip/hip_runtime.h>
#include <hip/hip_bf16.h>
#include <cstdint>

// ---------------------------------------------------------------------------
// TransformerClassifier: 2x single-head attention (N=4, L=2048, D=1024) +
// mean-pool + linear + sigmoid.  All math on MFMA via bf16 hi/lo split
// (3-pass: hh + hl + lh) for ~fp32-equivalent accuracy at bf16 MFMA rate.
//
// GEMM v4 = v3 with MFMA clusters reordered PASS-MAJOR: all hh, then all
// hl, then all lh.  v3's {hh,hl,lh} per (i,j) created 3-deep dependent
// MFMA chains on the same accumulator (schedule-invariant ~40% MfmaUtil
// across R2-R5); pass-major gives 4-8 independent MFMAs between any
// accumulator reuse, hiding MFMA result latency.
//
// ws layout unchanged (216 MB total).
// ---------------------------------------------------------------------------

#define DEVFN __device__ __forceinline__

typedef __attribute__((ext_vector_type(8))) short bf16x8;
typedef __attribute__((ext_vector_type(4))) float f32x4;
typedef unsigned short u16;

DEVFN u16 f2bf(float f) {               // round-to-nearest-even bf16 (finite)
    uint32_t x = __float_as_uint(f);
    x += 0x7fffu + ((x >> 16) & 1u);
    return (u16)(x >> 16);
}
DEVFN float bf2f(u16 u) { return __uint_as_float(((uint32_t)u) << 16); }
DEVFN void split2(float v, u16& h, u16& l) {
    h = f2bf(v);
    l = f2bf(v - bf2f(h));              // exact residual
}

DEVFN void gload_lds16(const void* g, void* l) {
    __builtin_amdgcn_global_load_lds(
        (const __attribute__((address_space(1))) void*)g,
        (__attribute__((address_space(3))) void*)l, 16, 0, 0);
}

#define MFMA_BF16 __builtin_amdgcn_mfma_f32_16x16x32_bf16

// ---------------------------------------------------------------------------
// 3-pass split-bf16 GEMM:  C = scale * (A . B^T)
//   A : M x K row-major (hi/lo, shared lda); B^T : N x K row-major (hi/lo)
// BN = 256 fixed.  Requires M%BM==0, N%256==0, K%32==0, K/32>=2,
// grid (N/256, M/BM, Z), total blocks % 8 == 0.
// EPI: 0 = hi/lo split row-major; 1 = fp32 row-major; 2 = V^T split
// ---------------------------------------------------------------------------
template<int BM, int EPI>
__global__ __launch_bounds__(512, 2) void gemm3(
    const u16* __restrict__ Ahi, const u16* __restrict__ Alo, long long aStride,
    const u16* __restrict__ Bhi, const u16* __restrict__ Blo, long long bStride,
    void* __restrict__ out0, void* __restrict__ out1, long long cStride,
    int M, int N, int K, int lda, int ldb, int ldc, float scale)
{
    constexpr int BUFSZ = BM * 64 + 16384;   // u16 per buffer (A + B sections)
    constexpr int AU    = BM / 64;           // A stage units per thread (4|2)
    constexpr int NU    = AU + 4;            // total stage units (8|6)
    constexpr int HF    = BM / 64;           // A-frag pairs per half (4|2)

    __shared__ __align__(16) u16 L[2 * BUFSZ];
    const int tid  = threadIdx.x;
    const int wave = tid >> 6, lane = tid & 63;

    // bijective XCD-aware block swizzle (all launches have nwg % 8 == 0)
    const int gx = gridDim.x, gy = gridDim.y;
    const int nwg = gx * gy * gridDim.z;
    int flat = (blockIdx.z * gy + blockIdx.y) * gx + blockIdx.x;
    flat = (flat & 7) * (nwg >> 3) + (flat >> 3);
    const int bx = flat % gx, by = (flat / gx) % gy, bz = flat / (gx * gy);

    const u16* pAhi = Ahi + (size_t)bz * aStride;
    const u16* pAlo = Alo + (size_t)bz * aStride;
    const u16* pBhi = Bhi + (size_t)bz * bStride;
    const u16* pBlo = Blo + (size_t)bz * bStride;
    const int m0 = by * BM, n0 = bx * 256;

    // ---- staging: unit q covers linear u16 range [q*4096, q*4096+4096)
    // of a buffer section; thread covers slot s = q*512 + tid ->
    // (row = s>>3, slot = s&7), stored chunk = slot ^ (row&7).
    const u16* src[NU];
    int dst[NU];
#pragma unroll
    for (int q = 0; q < AU; q++) {
        const int s = q * 512 + tid, row = s >> 3, c = (s & 7) ^ (row & 7);
        src[q] = (c < 4 ? pAhi : pAlo) + (size_t)(m0 + row) * lda + (c & 3) * 8;
        dst[q] = q * 4096 + wave * 512;
    }
#pragma unroll
    for (int q = 0; q < 4; q++) {
        const int s = q * 512 + tid, row = s >> 3, c = (s & 7) ^ (row & 7);
        src[AU + q] = (c < 4 ? pBhi : pBlo) + (size_t)(n0 + row) * ldb + (c & 3) * 8;
        dst[AU + q] = BM * 64 + q * 4096 + wave * 512;
    }

    // ---- fragment geometry
    const int fr = lane & 15, ch = lane >> 4;        // row-in-frag, hi k-chunk
    const int wm = (wave >> 2) * (BM / 2);           // 2M x 4N decomposition
    const int wn = (wave & 3) * 64;

    const int NT = K >> 5;

    // ---- prologue: stage tile 0 into buffer 0
#pragma unroll
    for (int u = 0; u < NU; u++) { gload_lds16(src[u], &L[dst[u]]); src[u] += 32; }
    asm volatile("s_waitcnt vmcnt(0)" ::: "memory");
    __builtin_amdgcn_s_barrier();

    f32x4 acc[2 * HF][4] = {};
    bf16x8 ah[HF], al[HF], bh[4], bl[4];
    int cOff = 0;

#define STAGE(u) do { gload_lds16(src[u], &L[sOff + dst[u]]); src[u] += 32; } while (0)
#define PH_SYNC  __builtin_amdgcn_s_barrier();                                 \
                 asm volatile("s_waitcnt lgkmcnt(0)" ::: "memory");            \
                 __builtin_amdgcn_sched_barrier(0);                            \
                 __builtin_amdgcn_s_setprio(1)
#define PH_END   __builtin_amdgcn_s_setprio(0);                                \
                 __builtin_amdgcn_s_barrier()

    for (int kt = 0; kt < NT; ++kt) {
        const int sOff = cOff ^ BUFSZ;
        const bool pre = (kt + 1) < NT;

        // ---- phase 0: read A half0 + B j0,j1; stage 0,1; quad (0,0)
#pragma unroll
        for (int i = 0; i < HF; i++) {
            const int r = wm + i * 16 + fr;
            const int x = cOff + r * 64 + ((ch ^ (r & 7)) << 3);
            ah[i] = *(const bf16x8*)&L[x];
            al[i] = *(const bf16x8*)&L[x ^ 32];
        }
#pragma unroll
        for (int j = 0; j < 2; j++) {
            const int r = wn + j * 16 + fr;
            const int x = cOff + BM * 64 + r * 64 + ((ch ^ (r & 7)) << 3);
            bh[j] = *(const bf16x8*)&L[x];
            bl[j] = *(const bf16x8*)&L[x ^ 32];
        }
        if (pre) { STAGE(0); STAGE(1); }
        PH_SYNC;
        // pass-major: hh sweep, hl sweep, lh sweep (no dependent chains)
#pragma unroll
        for (int i = 0; i < HF; i++)
#pragma unroll
            for (int j = 0; j < 2; j++)
                acc[i][j] = MFMA_BF16(ah[i], bh[j], acc[i][j], 0, 0, 0);
#pragma unroll
        for (int i = 0; i < HF; i++)
#pragma unroll
            for (int j = 0; j < 2; j++)
                acc[i][j] = MFMA_BF16(ah[i], bl[j], acc[i][j], 0, 0, 0);
#pragma unroll
        for (int i = 0; i < HF; i++)
#pragma unroll
            for (int j = 0; j < 2; j++)
                acc[i][j] = MFMA_BF16(al[i], bh[j], acc[i][j], 0, 0, 0);
        PH_END;

        // ---- phase 1: read B j2,j3; stage 2,3; quad (0,1)
#pragma unroll
        for (int j = 2; j < 4; j++) {
            const int r = wn + j * 16 + fr;
            const int x = cOff + BM * 64 + r * 64 + ((ch ^ (r & 7)) << 3);
            bh[j] = *(const bf16x8*)&L[x];
            bl[j] = *(const bf16x8*)&L[x ^ 32];
        }
        if (pre) { STAGE(2); STAGE(3); }
        PH_SYNC;
#pragma unroll
        for (int i = 0; i < HF; i++)
#pragma unroll
            for (int j = 2; j < 4; j++)
                acc[i][j] = MFMA_BF16(ah[i], bh[j], acc[i][j], 0, 0, 0);
#pragma unroll
        for (int i = 0; i < HF; i++)
#pragma unroll
            for (int j = 2; j < 4; j++)
                acc[i][j] = MFMA_BF16(ah[i], bl[j], acc[i][j], 0, 0, 0);
#pragma unroll
        for (int i = 0; i < HF; i++)
#pragma unroll
            for (int j = 2; j < 4; j++)
                acc[i][j] = MFMA_BF16(al[i], bh[j], acc[i][j], 0, 0, 0);
        PH_END;

        // ---- phase 2: read A half1; stage 4,5; quad (1,0)
#pragma unroll
        for (int i = 0; i < HF; i++) {
            const int r = wm + (BM / 4) + i * 16 + fr;
            const int x = cOff + r * 64 + ((ch ^ (r & 7)) << 3);
            ah[i] = *(const bf16x8*)&L[x];
            al[i] = *(const bf16x8*)&L[x ^ 32];
        }
        if (pre) { STAGE(4); STAGE(5); }
        PH_SYNC;
#pragma unroll
        for (int i = 0; i < HF; i++)
#pragma unroll
            for (int j = 0; j < 2; j++)
                acc[HF + i][j] = MFMA_BF16(ah[i], bh[j], acc[HF + i][j], 0, 0, 0);
#pragma unroll
        for (int i = 0; i < HF; i++)
#pragma unroll
            for (int j = 0; j < 2; j++)
                acc[HF + i][j] = MFMA_BF16(ah[i], bl[j], acc[HF + i][j], 0, 0, 0);
#pragma unroll
        for (int i = 0; i < HF; i++)
#pragma unroll
            for (int j = 0; j < 2; j++)
                acc[HF + i][j] = MFMA_BF16(al[i], bh[j], acc[HF + i][j], 0, 0, 0);
        PH_END;

        // ---- phase 3: no reads; stage 6,7 (BM=256 only); quad (1,1)
        if (pre) {
            if constexpr (NU > 6) { STAGE(6); STAGE(7); }
        }
        __builtin_amdgcn_s_setprio(1);
#pragma unroll
        for (int i = 0; i < HF; i++)
#pragma unroll
            for (int j = 2; j < 4; j++)
                acc[HF + i][j] = MFMA_BF16(ah[i], bh[j], acc[HF + i][j], 0, 0, 0);
#pragma unroll
        for (int i = 0; i < HF; i++)
#pragma unroll
            for (int j = 2; j < 4; j++)
                acc[HF + i][j] = MFMA_BF16(ah[i], bl[j], acc[HF + i][j], 0, 0, 0);
#pragma unroll
        for (int i = 0; i < HF; i++)
#pragma unroll
            for (int j = 2; j < 4; j++)
                acc[HF + i][j] = MFMA_BF16(al[i], bh[j], acc[HF + i][j], 0, 0, 0);
        __builtin_amdgcn_s_setprio(0);

        // ---- K-tile boundary
        if (pre) asm volatile("s_waitcnt vmcnt(0)" ::: "memory");
        __builtin_amdgcn_sched_barrier(0);
        __builtin_amdgcn_s_barrier();
        cOff = sOff;
    }
#undef STAGE
#undef PH_SYNC
#undef PH_END

    // ---- epilogue: C/D layout col = lane&15, row = (lane>>4)*4 + r
#pragma unroll
    for (int i = 0; i < 2 * HF; i++)
#pragma unroll
        for (int j = 0; j < 4; j++)
#pragma unroll
            for (int r = 0; r < 4; r++) {
                const int row = m0 + wm + i * 16 + (lane >> 4) * 4 + r;
                const int col = n0 + wn + j * 16 + (lane & 15);
                const float v = acc[i][j][r] * scale;
                if constexpr (EPI == 0) {
                    u16 h, l; split2(v, h, l);
                    const size_t off = (size_t)bz * cStride + (size_t)row * ldc + col;
                    ((u16*)out0)[off] = h;
                    ((u16*)out1)[off] = l;
                } else if constexpr (EPI == 1) {
                    ((float*)out0)[(size_t)bz * cStride + (size_t)row * ldc + col] = v;
                } else {  // EPI == 2 : V^T split, per-batch (L=2048, D=1024)
                    const int b = row >> 11, ll = row & 2047;
                    const size_t off = (size_t)b * (2048 * 1024) + (size_t)col * 2048 + ll;
                    u16 h, l; split2(v, h, l);
                    ((u16*)out0)[off] = h;
                    ((u16*)out1)[off] = l;
                }
            }
}

// ---------------------------------------------------------------------------
__global__ __launch_bounds__(256) void split_f32(
    const float* __restrict__ x, u16* __restrict__ hi, u16* __restrict__ lo)
{
    const size_t i = ((size_t)blockIdx.x * 256 + threadIdx.x) * 4;
    const float4 v = *(const float4*)&x[i];
    ushort4 h, l;
    split2(v.x, h.x, l.x); split2(v.y, h.y, l.y);
    split2(v.z, h.z, l.z); split2(v.w, h.w, l.w);
    *(ushort4*)&hi[i] = h;
    *(ushort4*)&lo[i] = l;
}

// ---------------------------------------------------------------------------
__global__ __launch_bounds__(256) void transpose_split(
    const float* __restrict__ W, u16* __restrict__ thi, u16* __restrict__ tlo)
{
    __shared__ float t[64][65];
    const int tid = threadIdx.x;
    const int r0 = blockIdx.y * 64, c0 = blockIdx.x * 64;
#pragma unroll
    for (int it = 0; it < 16; it++) {
        const int idx = it * 256 + tid, rr = idx >> 6, cc = idx & 63;
        t[rr][cc] = W[(size_t)(r0 + rr) * 1024 + (c0 + cc)];
    }
    __syncthreads();
#pragma unroll
    for (int it = 0; it < 16; it++) {
        const int idx = it * 256 + tid, nn = idx >> 6, kk = idx & 63;
        const float v = t[kk][nn];
        u16 h, l; split2(v, h, l);
        const size_t off = (size_t)(c0 + nn) * 1024 + (r0 + kk);
        thi[off] = h;
        tlo[off] = l;
    }
}

// ---------------------------------------------------------------------------
// Row softmax over 2048 fp32 scores, written IN PLACE as P hi/lo bf16
// ---------------------------------------------------------------------------
__global__ __launch_bounds__(256) void softmax_rows(float* __restrict__ S)
{
    const int r   = blockIdx.x;                 // 0..8191 (batch*2048 + l)
    float* row    = S + (size_t)r * 2048;
    const int tid = threadIdx.x;

    const float4 a = *(const float4*)&row[tid * 8];
    const float4 b = *(const float4*)&row[tid * 8 + 4];
    float v[8] = {a.x, a.y, a.z, a.w, b.x, b.y, b.z, b.w};

    float m = v[0];
#pragma unroll
    for (int j = 1; j < 8; j++) m = fmaxf(m, v[j]);
    for (int o = 32; o; o >>= 1) m = fmaxf(m, __shfl_xor(m, o));
    __shared__ float redm[4], reds[4];
    if ((tid & 63) == 0) redm[tid >> 6] = m;
    __syncthreads();
    m = fmaxf(fmaxf(redm[0], redm[1]), fmaxf(redm[2], redm[3]));

    float e[8], s = 0.f;
#pragma unroll
    for (int j = 0; j < 8; j++) { e[j] = __expf(v[j] - m); s += e[j]; }
    for (int o = 32; o; o >>= 1) s += __shfl_xor(s, o);
    if ((tid & 63) == 0) reds[tid >> 6] = s;
    __syncthreads();
    s = reds[0] + reds[1] + reds[2] + reds[3];
    const float inv = 1.f / s;

    u16* ph = (u16*)row;
    u16* pl = ph + 2048;
#pragma unroll
    for (int j = 0; j < 8; j++) {
        u16 h, l; split2(e[j] * inv, h, l);
        ph[tid * 8 + j] = h;
        pl[tid * 8 + j] = l;
    }
}

// ---------------------------------------------------------------------------
__global__ __launch_bounds__(256) void pool_partial(
    const float* __restrict__ H2, const float* __restrict__ wO,
    float* __restrict__ partial)
{
    const int b = blockIdx.x, chunk = blockIdx.y;
    const int tid = threadIdx.x;
    const float* Hb = H2 + (size_t)b * 2048 * 1024 + (size_t)chunk * 64 * 1024;
    const float4 w = *(const float4*)&wO[tid * 4];
    float acc = 0.f;
#pragma unroll 4
    for (int l = 0; l < 64; l++) {
        const float4 h = *(const float4*)&Hb[(size_t)l * 1024 + tid * 4];
        acc += h.x * w.x + h.y * w.y + h.z * w.z + h.w * w.w;
    }
    for (int o = 32; o; o >>= 1) acc += __shfl_xor(acc, o);
    __shared__ float red[4];
    if ((tid & 63) == 0) red[tid >> 6] = acc;
    __syncthreads();
    if (tid == 0) partial[b * 32 + chunk] = red[0] + red[1] + red[2] + red[3];
}

__global__ void head_final(const float* __restrict__ partial,
                           const float* __restrict__ bO, float* __restrict__ out)
{
    const int b = threadIdx.x;                  // 0..3
    if (b >= 4) return;
    float s = 0.f;
#pragma unroll
    for (int c = 0; c < 32; c++) s += partial[b * 32 + c];
    const float logit = s * (1.f / 2048.f) + bO[0];
    out[b] = 1.f / (1.f + __expf(-logit));
}

// ---------------------------------------------------------------------------
extern "C" void kernel_launch(void* const* d_in, const int* in_sizes, int n_in,
                              void* d_out, int out_size, void* d_ws, size_t ws_size,
                              hipStream_t stream)
{
    const float* X   = (const float*)d_in[0];
    const float* Wq1 = (const float*)d_in[1];
    const float* Wk1 = (const float*)d_in[2];
    const float* Wv1 = (const float*)d_in[3];
    const float* Wq2 = (const float*)d_in[4];
    const float* Wk2 = (const float*)d_in[5];
    const float* Wv2 = (const float*)d_in[6];
    const float* WO  = (const float*)d_in[7];
    const float* bO  = (const float*)d_in[8];
    float* out = (float*)d_out;

    uint8_t* ws = (uint8_t*)d_ws;
    const size_t MB = 1ull << 20;
    u16* Ahi  = (u16*)(ws + 0);        u16* Alo  = (u16*)(ws + 16 * MB);
    u16* Qhi  = (u16*)(ws + 32 * MB);  u16* Qlo  = (u16*)(ws + 48 * MB);
    u16* Khi  = (u16*)(ws + 64 * MB);  u16* Klo  = (u16*)(ws + 80 * MB);
    u16* Vthi = (u16*)(ws + 96 * MB);  u16* Vtlo = (u16*)(ws + 112 * MB);
    u16* Wt   = (u16*)(ws + 128 * MB);               // 6 x (hi 1M + lo 1M) u16
    float* S  = (float*)(ws + 152 * MB);             // 64 MB scores / P
    float* H2 = (float*)(ws + 32 * MB);              // aliases Q (dead by then)
    float* partial = (float*)(ws + 64 * MB);         // aliases K (dead by then)

    auto Wh = [&](int i) { return Wt + (size_t)i * 2097152; };
    auto Wl = [&](int i) { return Wt + (size_t)i * 2097152 + 1048576; };
    const float* Wsrc[6] = {Wq1, Wk1, Wv1, Wq2, Wk2, Wv2};

    // ---- prep: split X, transpose+split weights
    split_f32<<<8192, 256, 0, stream>>>(X, Ahi, Alo);   // 8M elems
    for (int i = 0; i < 6; i++)
        transpose_split<<<dim3(16, 16), 256, 0, stream>>>(Wsrc[i], Wh(i), Wl(i));

    const long long LD2 = 2048LL * 1024;   // 2M: Q/K/V & H batch stride
    const long long SST = 2048LL * 2048;   // 4M: S batch stride (floats)
    const long long PST = 2048LL * 4096;   // 8M: P batch stride (u16)

    for (int blk = 0; blk < 2; blk++) {
        const int w0 = blk * 3;
        // projections: BM=128, BN=256 -> grid (1024/256=4, 8192/128=64) = 256
        gemm3<128, 0><<<dim3(4, 64, 1), 512, 0, stream>>>(
            Ahi, Alo, 0, Wh(w0 + 0), Wl(w0 + 0), 0, Qhi, Qlo, 0,
            8192, 1024, 1024, 1024, 1024, 1024, 1.f);
        gemm3<128, 0><<<dim3(4, 64, 1), 512, 0, stream>>>(
            Ahi, Alo, 0, Wh(w0 + 1), Wl(w0 + 1), 0, Khi, Klo, 0,
            8192, 1024, 1024, 1024, 1024, 1024, 1.f);
        gemm3<128, 2><<<dim3(4, 64, 1), 512, 0, stream>>>(
            Ahi, Alo, 0, Wh(w0 + 2), Wl(w0 + 2), 0, Vthi, Vtlo, 0,
            8192, 1024, 1024, 1024, 1024, 1024, 1.f);
        // S = Q.K^T / sqrt(D): BM=256 -> grid (2048/256=8, 2048/256=8, 4) = 256
        gemm3<256, 1><<<dim3(8, 8, 4), 512, 0, stream>>>(
            Qhi, Qlo, LD2, Khi, Klo, LD2, S, nullptr, SST,
            2048, 2048, 1024, 1024, 1024, 2048, 0.03125f);
        // softmax rows, in-place -> P hi/lo
        softmax_rows<<<8192, 256, 0, stream>>>(S);
        // O = P.V: BM=128 -> grid (1024/256=4, 2048/128=16, 4) = 256
        if (blk == 0) {
            gemm3<128, 0><<<dim3(4, 16, 4), 512, 0, stream>>>(
                (u16*)S, (u16*)S + 2048, PST, Vthi, Vtlo, LD2, Ahi, Alo, LD2,
                2048, 1024, 2048, 4096, 2048, 1024, 1.f);   // H1 split -> A region
        } else {
            gemm3<128, 1><<<dim3(4, 16, 4), 512, 0, stream>>>(
                (u16*)S, (u16*)S + 2048, PST, Vthi, Vtlo, LD2, H2, nullptr, LD2,
                2048, 1024, 2048, 4096, 2048, 1024, 1.f);   // H2 fp32
        }
    }

    pool_partial<<<dim3(4, 32), 256, 0, stream>>>(H2, WO, partial);
    head_final<<<1, 64, 0, stream>>>(partial, bO, out);
}

// Round 7
// 601.672 us; speedup vs baseline: 1.9962x; 1.2837x over previous
//
#include <hip/hip_runtime.h>
#include <hip/hip_bf16.h>
#include <cstdint>

// ---------------------------------------------------------------------------
// TransformerClassifier: 2x single-head attention (N=4, L=2048, D=1024) +
// mean-pool + linear + sigmoid.
//
// GEMM v5: 2-PASS split-A scheme:  C = scale * ((Ahi + Alo) . Bh^T)
//   A carries full ~16-bit precision (bf16 hi/lo); B is single bf16.
//   Residual error = a.(b - bh) ~ 1.7e-4 relative per dot -- well under the
//   1.76e-2 output threshold (R6 absmax was 0.0 with 3-pass).
//   vs 3-pass: 33% fewer MFMAs, B staging/LDS/fetch halved.
//
// Structure: BN=256, BM templated (256 QK^T / 128 proj+PV), 512 thr =
// 8 waves 2M x 4N, BK=32, double-buffered LDS, 4 quadrant-phases per
// K-tile (16 MFMA/phase at BM=256), counted staging with vmcnt(0) once
// per K-tile.  A LDS rows = 8x16B slots (hi 0-3, lo 4-7), swizzle
// slot = chunk ^ (row&7); B LDS rows = 4x16B slots (hi only), swizzle
// slot = chunk ^ ((row>>1)&3).  Swizzles realized by pre-swizzled GLOBAL
// source addresses (global_load_lds dest stays linear, rule #21).
//
// ws layout (u16 regions; 216 MB total, some lo regions now unused):
//   [  0MB) Ahi/Alo : X split, later H1 split      (16+16 MB)
//   [ 32MB) Qhi/Qlo : Q split; later H2 fp32       (16+16 MB)
//   [ 64MB) Khi     : K hi (lo region free)        (16 MB) + partials
//   [ 96MB) Vthi    : V^T hi (lo region free)      (16 MB)
//   [128MB) Wt      : 6x W^T hi (2MB each)         (12 MB)
//   [152MB) S/P     : scores fp32 -> P hi/lo in place (64 MB)
// ---------------------------------------------------------------------------

#define DEVFN __device__ __forceinline__

typedef __attribute__((ext_vector_type(8))) short bf16x8;
typedef __attribute__((ext_vector_type(4))) float f32x4;
typedef unsigned short u16;

DEVFN u16 f2bf(float f) {               // round-to-nearest-even bf16 (finite)
    uint32_t x = __float_as_uint(f);
    x += 0x7fffu + ((x >> 16) & 1u);
    return (u16)(x >> 16);
}
DEVFN float bf2f(u16 u) { return __uint_as_float(((uint32_t)u) << 16); }
DEVFN void split2(float v, u16& h, u16& l) {
    h = f2bf(v);
    l = f2bf(v - bf2f(h));              // exact residual
}

DEVFN void gload_lds16(const void* g, void* l) {
    __builtin_amdgcn_global_load_lds(
        (const __attribute__((address_space(1))) void*)g,
        (__attribute__((address_space(3))) void*)l, 16, 0, 0);
}

#define MFMA_BF16 __builtin_amdgcn_mfma_f32_16x16x32_bf16

// ---------------------------------------------------------------------------
// 2-pass split-A GEMM:  C = scale * ((Ahi+Alo) . Bh^T)
//   A : M x K row-major hi/lo (shared lda);  Bh : N x K row-major bf16
// BN = 256 fixed.  Requires M%BM==0, N%256==0, K%32==0, K/32>=2,
// grid (N/256, M/BM, Z), total blocks % 8 == 0.
// EPI: 0 = hi/lo split row-major; 1 = fp32 row-major;
//      2 = V^T hi-only per-batch;  3 = hi-only row-major
// ---------------------------------------------------------------------------
template<int BM, int EPI>
__global__ __launch_bounds__(512, 2) void gemm2(
    const u16* __restrict__ Ahi, const u16* __restrict__ Alo, long long aStride,
    const u16* __restrict__ Bh, long long bStride,
    void* __restrict__ out0, void* __restrict__ out1, long long cStride,
    int M, int N, int K, int lda, int ldb, int ldc, float scale)
{
    constexpr int ASEC  = BM * 64;           // u16 per buffer, A section
    constexpr int BUFSZ = ASEC + 8192;       // + B section (256 rows x 32 u16)
    constexpr int AU    = BM / 64;           // A stage units (4|2)
    constexpr int NU    = AU + 2;            // total stage units (6|4)
    constexpr int HF    = BM / 64;           // A-frag pairs per half (4|2)

    __shared__ __align__(16) u16 L[2 * BUFSZ];
    const int tid  = threadIdx.x;
    const int wave = tid >> 6, lane = tid & 63;

    // bijective XCD-aware block swizzle (all launches have nwg % 8 == 0)
    const int gx = gridDim.x, gy = gridDim.y;
    const int nwg = gx * gy * gridDim.z;
    int flat = (blockIdx.z * gy + blockIdx.y) * gx + blockIdx.x;
    flat = (flat & 7) * (nwg >> 3) + (flat >> 3);
    const int bx = flat % gx, by = (flat / gx) % gy, bz = flat / (gx * gy);

    const u16* pAhi = Ahi + (size_t)bz * aStride;
    const u16* pAlo = Alo + (size_t)bz * aStride;
    const u16* pBh  = Bh  + (size_t)bz * bStride;
    const int m0 = by * BM, n0 = bx * 256;

    // ---- staging unit setup (pre-swizzled global sources, linear LDS dest)
    const u16* src[NU];
    int dst[NU];
#pragma unroll
    for (int q = 0; q < AU; q++) {           // A: 8 slots/row, chunk = slot^(row&7)
        const int s = q * 512 + tid, row = s >> 3, c = (s & 7) ^ (row & 7);
        src[q] = (c < 4 ? pAhi : pAlo) + (size_t)(m0 + row) * lda + (c & 3) * 8;
        dst[q] = q * 4096 + wave * 512;
    }
#pragma unroll
    for (int q = 0; q < 2; q++) {            // B: 4 slots/row, chunk = slot^((row>>1)&3)
        const int s = q * 512 + tid, row = s >> 2, c = (s & 3) ^ ((row >> 1) & 3);
        src[AU + q] = pBh + (size_t)(n0 + row) * ldb + c * 8;
        dst[AU + q] = ASEC + q * 4096 + wave * 512;
    }

    // ---- fragment geometry
    const int fr = lane & 15, ch = lane >> 4;        // row-in-frag, k-chunk
    const int wm = (wave >> 2) * (BM / 2);           // 2M x 4N decomposition
    const int wn = (wave & 3) * 64;

    const int NT = K >> 5;

    // ---- prologue: stage tile 0 into buffer 0
#pragma unroll
    for (int u = 0; u < NU; u++) { gload_lds16(src[u], &L[dst[u]]); src[u] += 32; }
    asm volatile("s_waitcnt vmcnt(0)" ::: "memory");
    __builtin_amdgcn_s_barrier();

    f32x4 acc[2 * HF][4] = {};
    bf16x8 ah[HF], al[HF], bh[4];
    int cOff = 0;

#define STAGE(u) do { gload_lds16(src[u], &L[sOff + dst[u]]); src[u] += 32; } while (0)
#define PH_SYNC  __builtin_amdgcn_s_barrier();                                 \
                 asm volatile("s_waitcnt lgkmcnt(0)" ::: "memory");            \
                 __builtin_amdgcn_sched_barrier(0);                            \
                 __builtin_amdgcn_s_setprio(1)
#define PH_END   __builtin_amdgcn_s_setprio(0);                                \
                 __builtin_amdgcn_s_barrier()

    for (int kt = 0; kt < NT; ++kt) {
        const int sOff = cOff ^ BUFSZ;
        const bool pre = (kt + 1) < NT;

        // ---- phase 0: read A half0 + B j0,j1; quad (0,0)
#pragma unroll
        for (int i = 0; i < HF; i++) {
            const int r = wm + i * 16 + fr;
            const int x = cOff + r * 64 + ((ch ^ (r & 7)) << 3);
            ah[i] = *(const bf16x8*)&L[x];
            al[i] = *(const bf16x8*)&L[x ^ 32];
        }
#pragma unroll
        for (int j = 0; j < 2; j++) {
            const int r = wn + j * 16 + fr;
            const int x = cOff + ASEC + r * 32 + ((ch ^ ((r >> 1) & 3)) << 3);
            bh[j] = *(const bf16x8*)&L[x];
        }
        if (pre) { STAGE(0); if constexpr (NU > 4) STAGE(1); }
        PH_SYNC;
#pragma unroll
        for (int i = 0; i < HF; i++)
#pragma unroll
            for (int j = 0; j < 2; j++)
                acc[i][j] = MFMA_BF16(ah[i], bh[j], acc[i][j], 0, 0, 0);
#pragma unroll
        for (int i = 0; i < HF; i++)
#pragma unroll
            for (int j = 0; j < 2; j++)
                acc[i][j] = MFMA_BF16(al[i], bh[j], acc[i][j], 0, 0, 0);
        PH_END;

        // ---- phase 1: read B j2,j3; quad (0,1)
#pragma unroll
        for (int j = 2; j < 4; j++) {
            const int r = wn + j * 16 + fr;
            const int x = cOff + ASEC + r * 32 + ((ch ^ ((r >> 1) & 3)) << 3);
            bh[j] = *(const bf16x8*)&L[x];
        }
        if (pre) { if constexpr (NU > 4) { STAGE(2); STAGE(3); } else STAGE(1); }
        PH_SYNC;
#pragma unroll
        for (int i = 0; i < HF; i++)
#pragma unroll
            for (int j = 2; j < 4; j++)
                acc[i][j] = MFMA_BF16(ah[i], bh[j], acc[i][j], 0, 0, 0);
#pragma unroll
        for (int i = 0; i < HF; i++)
#pragma unroll
            for (int j = 2; j < 4; j++)
                acc[i][j] = MFMA_BF16(al[i], bh[j], acc[i][j], 0, 0, 0);
        PH_END;

        // ---- phase 2: read A half1; quad (1,0)
#pragma unroll
        for (int i = 0; i < HF; i++) {
            const int r = wm + (BM / 4) + i * 16 + fr;
            const int x = cOff + r * 64 + ((ch ^ (r & 7)) << 3);
            ah[i] = *(const bf16x8*)&L[x];
            al[i] = *(const bf16x8*)&L[x ^ 32];
        }
        if (pre) { if constexpr (NU > 4) STAGE(4); else STAGE(2); }
        PH_SYNC;
#pragma unroll
        for (int i = 0; i < HF; i++)
#pragma unroll
            for (int j = 0; j < 2; j++)
                acc[HF + i][j] = MFMA_BF16(ah[i], bh[j], acc[HF + i][j], 0, 0, 0);
#pragma unroll
        for (int i = 0; i < HF; i++)
#pragma unroll
            for (int j = 0; j < 2; j++)
                acc[HF + i][j] = MFMA_BF16(al[i], bh[j], acc[HF + i][j], 0, 0, 0);
        PH_END;

        // ---- phase 3: no reads; quad (1,1)
        if (pre) { if constexpr (NU > 4) STAGE(5); else STAGE(3); }
        __builtin_amdgcn_s_setprio(1);
#pragma unroll
        for (int i = 0; i < HF; i++)
#pragma unroll
            for (int j = 2; j < 4; j++)
                acc[HF + i][j] = MFMA_BF16(ah[i], bh[j], acc[HF + i][j], 0, 0, 0);
#pragma unroll
        for (int i = 0; i < HF; i++)
#pragma unroll
            for (int j = 2; j < 4; j++)
                acc[HF + i][j] = MFMA_BF16(al[i], bh[j], acc[HF + i][j], 0, 0, 0);
        __builtin_amdgcn_s_setprio(0);

        // ---- K-tile boundary
        if (pre) asm volatile("s_waitcnt vmcnt(0)" ::: "memory");
        __builtin_amdgcn_sched_barrier(0);
        __builtin_amdgcn_s_barrier();
        cOff = sOff;
    }
#undef STAGE
#undef PH_SYNC
#undef PH_END

    // ---- epilogue: C/D layout col = lane&15, row = (lane>>4)*4 + r
#pragma unroll
    for (int i = 0; i < 2 * HF; i++)
#pragma unroll
        for (int j = 0; j < 4; j++)
#pragma unroll
            for (int r = 0; r < 4; r++) {
                const int row = m0 + wm + i * 16 + (lane >> 4) * 4 + r;
                const int col = n0 + wn + j * 16 + (lane & 15);
                const float v = acc[i][j][r] * scale;
                if constexpr (EPI == 0) {
                    u16 h, l; split2(v, h, l);
                    const size_t off = (size_t)bz * cStride + (size_t)row * ldc + col;
                    ((u16*)out0)[off] = h;
                    ((u16*)out1)[off] = l;
                } else if constexpr (EPI == 1) {
                    ((float*)out0)[(size_t)bz * cStride + (size_t)row * ldc + col] = v;
                } else if constexpr (EPI == 2) {  // V^T hi-only, per-batch
                    const int b = row >> 11, ll = row & 2047;
                    ((u16*)out0)[(size_t)b * (2048 * 1024) + (size_t)col * 2048 + ll] = f2bf(v);
                } else {                          // EPI == 3: hi-only row-major
                    ((u16*)out0)[(size_t)bz * cStride + (size_t)row * ldc + col] = f2bf(v);
                }
            }
}

// ---------------------------------------------------------------------------
__global__ __launch_bounds__(256) void split_f32(
    const float* __restrict__ x, u16* __restrict__ hi, u16* __restrict__ lo)
{
    const size_t i = ((size_t)blockIdx.x * 256 + threadIdx.x) * 4;
    const float4 v = *(const float4*)&x[i];
    ushort4 h, l;
    split2(v.x, h.x, l.x); split2(v.y, h.y, l.y);
    split2(v.z, h.z, l.z); split2(v.w, h.w, l.w);
    *(ushort4*)&hi[i] = h;
    *(ushort4*)&lo[i] = l;
}

// ---------------------------------------------------------------------------
// W (1024x1024 fp32 [d][k]) -> W^T hi bf16 ([k][d])
// ---------------------------------------------------------------------------
__global__ __launch_bounds__(256) void transpose_hi(
    const float* __restrict__ W, u16* __restrict__ thi)
{
    __shared__ float t[64][65];
    const int tid = threadIdx.x;
    const int r0 = blockIdx.y * 64, c0 = blockIdx.x * 64;
#pragma unroll
    for (int it = 0; it < 16; it++) {
        const int idx = it * 256 + tid, rr = idx >> 6, cc = idx & 63;
        t[rr][cc] = W[(size_t)(r0 + rr) * 1024 + (c0 + cc)];
    }
    __syncthreads();
#pragma unroll
    for (int it = 0; it < 16; it++) {
        const int idx = it * 256 + tid, nn = idx >> 6, kk = idx & 63;
        thi[(size_t)(c0 + nn) * 1024 + (r0 + kk)] = f2bf(t[kk][nn]);
    }
}

// ---------------------------------------------------------------------------
// Row softmax over 2048 fp32 scores, written IN PLACE as P hi/lo bf16
// ---------------------------------------------------------------------------
__global__ __launch_bounds__(256) void softmax_rows(float* __restrict__ S)
{
    const int r   = blockIdx.x;                 // 0..8191 (batch*2048 + l)
    float* row    = S + (size_t)r * 2048;
    const int tid = threadIdx.x;

    const float4 a = *(const float4*)&row[tid * 8];
    const float4 b = *(const float4*)&row[tid * 8 + 4];
    float v[8] = {a.x, a.y, a.z, a.w, b.x, b.y, b.z, b.w};

    float m = v[0];
#pragma unroll
    for (int j = 1; j < 8; j++) m = fmaxf(m, v[j]);
    for (int o = 32; o; o >>= 1) m = fmaxf(m, __shfl_xor(m, o));
    __shared__ float redm[4], reds[4];
    if ((tid & 63) == 0) redm[tid >> 6] = m;
    __syncthreads();
    m = fmaxf(fmaxf(redm[0], redm[1]), fmaxf(redm[2], redm[3]));

    float e[8], s = 0.f;
#pragma unroll
    for (int j = 0; j < 8; j++) { e[j] = __expf(v[j] - m); s += e[j]; }
    for (int o = 32; o; o >>= 1) s += __shfl_xor(s, o);
    if ((tid & 63) == 0) reds[tid >> 6] = s;
    __syncthreads();
    s = reds[0] + reds[1] + reds[2] + reds[3];
    const float inv = 1.f / s;

    u16* ph = (u16*)row;
    u16* pl = ph + 2048;
#pragma unroll
    for (int j = 0; j < 8; j++) {
        u16 h, l; split2(e[j] * inv, h, l);
        ph[tid * 8 + j] = h;
        pl[tid * 8 + j] = l;
    }
}

// ---------------------------------------------------------------------------
__global__ __launch_bounds__(256) void pool_partial(
    const float* __restrict__ H2, const float* __restrict__ wO,
    float* __restrict__ partial)
{
    const int b = blockIdx.x, chunk = blockIdx.y;
    const int tid = threadIdx.x;
    const float* Hb = H2 + (size_t)b * 2048 * 1024 + (size_t)chunk * 64 * 1024;
    const float4 w = *(const float4*)&wO[tid * 4];
    float acc = 0.f;
#pragma unroll 4
    for (int l = 0; l < 64; l++) {
        const float4 h = *(const float4*)&Hb[(size_t)l * 1024 + tid * 4];
        acc += h.x * w.x + h.y * w.y + h.z * w.z + h.w * w.w;
    }
    for (int o = 32; o; o >>= 1) acc += __shfl_xor(acc, o);
    __shared__ float red[4];
    if ((tid & 63) == 0) red[tid >> 6] = acc;
    __syncthreads();
    if (tid == 0) partial[b * 32 + chunk] = red[0] + red[1] + red[2] + red[3];
}

__global__ void head_final(const float* __restrict__ partial,
                           const float* __restrict__ bO, float* __restrict__ out)
{
    const int b = threadIdx.x;                  // 0..3
    if (b >= 4) return;
    float s = 0.f;
#pragma unroll
    for (int c = 0; c < 32; c++) s += partial[b * 32 + c];
    const float logit = s * (1.f / 2048.f) + bO[0];
    out[b] = 1.f / (1.f + __expf(-logit));
}

// ---------------------------------------------------------------------------
extern "C" void kernel_launch(void* const* d_in, const int* in_sizes, int n_in,
                              void* d_out, int out_size, void* d_ws, size_t ws_size,
                              hipStream_t stream)
{
    const float* X   = (const float*)d_in[0];
    const float* Wq1 = (const float*)d_in[1];
    const float* Wk1 = (const float*)d_in[2];
    const float* Wv1 = (const float*)d_in[3];
    const float* Wq2 = (const float*)d_in[4];
    const float* Wk2 = (const float*)d_in[5];
    const float* Wv2 = (const float*)d_in[6];
    const float* WO  = (const float*)d_in[7];
    const float* bO  = (const float*)d_in[8];
    float* out = (float*)d_out;

    uint8_t* ws = (uint8_t*)d_ws;
    const size_t MB = 1ull << 20;
    u16* Ahi  = (u16*)(ws + 0);        u16* Alo  = (u16*)(ws + 16 * MB);
    u16* Qhi  = (u16*)(ws + 32 * MB);  u16* Qlo  = (u16*)(ws + 48 * MB);
    u16* Khi  = (u16*)(ws + 64 * MB);
    u16* Vthi = (u16*)(ws + 96 * MB);
    u16* Wt   = (u16*)(ws + 128 * MB);               // 6 x W^T hi (1M u16 each)
    float* S  = (float*)(ws + 152 * MB);             // 64 MB scores / P
    float* H2 = (float*)(ws + 32 * MB);              // aliases Q (dead by then)
    float* partial = (float*)(ws + 80 * MB);         // free region (old Klo)

    auto Wh = [&](int i) { return Wt + (size_t)i * 1048576; };
    const float* Wsrc[6] = {Wq1, Wk1, Wv1, Wq2, Wk2, Wv2};

    // ---- prep: split X, transpose weights (hi only)
    split_f32<<<8192, 256, 0, stream>>>(X, Ahi, Alo);   // 8M elems
    for (int i = 0; i < 6; i++)
        transpose_hi<<<dim3(16, 16), 256, 0, stream>>>(Wsrc[i], Wh(i));

    const long long LD2 = 2048LL * 1024;   // 2M: Q/K/V & H batch stride
    const long long SST = 2048LL * 2048;   // 4M: S batch stride (floats)
    const long long PST = 2048LL * 4096;   // 8M: P batch stride (u16)

    for (int blk = 0; blk < 2; blk++) {
        const int w0 = blk * 3;
        // projections: BM=128, BN=256 -> grid (4, 64) = 256 blocks
        gemm2<128, 0><<<dim3(4, 64, 1), 512, 0, stream>>>(
            Ahi, Alo, 0, Wh(w0 + 0), 0, Qhi, Qlo, 0,
            8192, 1024, 1024, 1024, 1024, 1024, 1.f);
        gemm2<128, 3><<<dim3(4, 64, 1), 512, 0, stream>>>(
            Ahi, Alo, 0, Wh(w0 + 1), 0, Khi, nullptr, 0,
            8192, 1024, 1024, 1024, 1024, 1024, 1.f);
        gemm2<128, 2><<<dim3(4, 64, 1), 512, 0, stream>>>(
            Ahi, Alo, 0, Wh(w0 + 2), 0, Vthi, nullptr, 0,
            8192, 1024, 1024, 1024, 1024, 1024, 1.f);
        // S = Q.K^T / sqrt(D): BM=256 -> grid (8, 8, 4) = 256 blocks
        gemm2<256, 1><<<dim3(8, 8, 4), 512, 0, stream>>>(
            Qhi, Qlo, LD2, Khi, LD2, S, nullptr, SST,
            2048, 2048, 1024, 1024, 1024, 2048, 0.03125f);
        // softmax rows, in-place -> P hi/lo
        softmax_rows<<<8192, 256, 0, stream>>>(S);
        // O = P.V: BM=128 -> grid (4, 16, 4) = 256 blocks
        if (blk == 0) {
            gemm2<128, 0><<<dim3(4, 16, 4), 512, 0, stream>>>(
                (u16*)S, (u16*)S + 2048, PST, Vthi, LD2, Ahi, Alo, LD2,
                2048, 1024, 2048, 4096, 2048, 1024, 1.f);   // H1 split -> A region
        } else {
            gemm2<128, 1><<<dim3(4, 16, 4), 512, 0, stream>>>(
                (u16*)S, (u16*)S + 2048, PST, Vthi, LD2, H2, nullptr, LD2,
                2048, 1024, 2048, 4096, 2048, 1024, 1.f);   // H2 fp32
        }
    }

    pool_partial<<<dim3(4, 32), 256, 0, stream>>>(H2, WO, partial);
    head_final<<<1, 64, 0, stream>>>(partial, bO, out);
}